// Round 3
// baseline (14342.105 us; speedup 1.0000x reference)
//
#include <hip/hip_runtime.h>

// Problem constants
#define BB 32
#define NN 2048
#define FF 3
#define HH 64
#define OUTC 128
#define KK 16
#define BN (BB * NN)   // 65536 points

#define SPLIT 2
#define CSZ3 (NN / SPLIT)  // 1024 candidates per knn3 partial scan

typedef __attribute__((ext_vector_type(8))) __bf16 bf16x8;
typedef __attribute__((ext_vector_type(4))) float f32x4;

// ---------------------------------------------------------------------------
// sq[p] = sum_d feat[p][d]^2
// ---------------------------------------------------------------------------
template <int D>
__global__ __launch_bounds__(256) void sq_kernel(const float* __restrict__ f,
                                                 float* __restrict__ sqo) {
    long p = (long)blockIdx.x * 256 + threadIdx.x;   // p < BN
    const float* fp = f + p * D;
    float s = 0.f;
#pragma unroll
    for (int d = 0; d < D; ++d) s = fmaf(fp[d], fp[d], s);
    sqo[p] = s;
}

// ---------------------------------------------------------------------------
// fp32 -> bf16 conversion (RNE). 8 elems per thread.
// ---------------------------------------------------------------------------
__global__ __launch_bounds__(256) void tobf16_kernel(const float* __restrict__ f,
                                                     __bf16* __restrict__ o) {
    long base = ((long)blockIdx.x * 256 + threadIdx.x) * 8;
    const float4* fp = (const float4*)(f + base);
    float4 v0 = fp[0], v1 = fp[1];
    unsigned short us[8];
    us[0] = __builtin_bit_cast(unsigned short, (__bf16)v0.x);
    us[1] = __builtin_bit_cast(unsigned short, (__bf16)v0.y);
    us[2] = __builtin_bit_cast(unsigned short, (__bf16)v0.z);
    us[3] = __builtin_bit_cast(unsigned short, (__bf16)v0.w);
    us[4] = __builtin_bit_cast(unsigned short, (__bf16)v1.x);
    us[5] = __builtin_bit_cast(unsigned short, (__bf16)v1.y);
    us[6] = __builtin_bit_cast(unsigned short, (__bf16)v1.z);
    us[7] = __builtin_bit_cast(unsigned short, (__bf16)v1.w);
    *(uint4*)(o + base) = *(const uint4*)us;
}

// ---------------------------------------------------------------------------
// kNN partial scan for D=3 (layer 0), candidate-split 2-way.
// ---------------------------------------------------------------------------
__global__ __launch_bounds__(256) void knn3_part_kernel(const float* __restrict__ x,
                                                        const float* __restrict__ sq,
                                                        float* __restrict__ pdist,
                                                        int* __restrict__ pidx) {
    __shared__ float4 lds_c[256];
    const int s = blockIdx.x & (SPLIT - 1);
    const int rbb = blockIdx.x / SPLIT;
    const int b = rbb >> 3;
    const int rb = rbb & 7;
    const int tid = threadIdx.x;
    const int row = rb * 256 + tid;
    const long pbase = (long)b * NN;

    const float* rp = x + (pbase + row) * 3;
    const float xr0 = rp[0], xr1 = rp[1], xr2 = rp[2];
    const float sqr = sq[pbase + row];

    float dist[KK];
    int idx[KK];
#pragma unroll
    for (int j = 0; j < KK; ++j) { dist[j] = 3.0e38f; idx[j] = 0; }

    for (int t = s * (CSZ3 / 256); t < (s + 1) * (CSZ3 / 256); ++t) {
        __syncthreads();
        {
            const int m = t * 256 + tid;
            const float* cp = x + (pbase + m) * 3;
            lds_c[tid] = make_float4(cp[0], cp[1], cp[2], sq[pbase + m]);
        }
        __syncthreads();
        for (int c = 0; c < 256; ++c) {
            float4 v = lds_c[c];
            float acc = 0.f;
            acc = fmaf(xr0, v.x, acc);
            acc = fmaf(xr1, v.y, acc);
            acc = fmaf(xr2, v.z, acc);
            float d2 = fmaf(-2.0f, acc, sqr + v.w);
            int m = t * 256 + c;
            if (d2 < dist[KK - 1]) {
                dist[KK - 1] = d2; idx[KK - 1] = m;
#pragma unroll
                for (int j = KK - 1; j > 0; --j) {
                    if (dist[j] < dist[j - 1]) {
                        float tf = dist[j]; dist[j] = dist[j - 1]; dist[j - 1] = tf;
                        int ti = idx[j]; idx[j] = idx[j - 1]; idx[j - 1] = ti;
                    }
                }
            }
        }
    }
    float* dp = pdist + ((pbase + row) * SPLIT + s) * KK;
    int* ip = pidx + ((pbase + row) * SPLIT + s) * KK;
#pragma unroll
    for (int j = 0; j < KK; ++j) { dp[j] = dist[j]; ip[j] = idx[j]; }
}

// ---------------------------------------------------------------------------
// Merge SPLIT sorted partial top-16 lists -> final top-16 indices per row.
// ---------------------------------------------------------------------------
__global__ __launch_bounds__(256) void knn_merge_kernel(const float* __restrict__ pdist,
                                                        const int* __restrict__ pidx,
                                                        int* __restrict__ idx_out) {
    long p = (long)blockIdx.x * 256 + threadIdx.x;
    const float* dp = pdist + p * (SPLIT * KK);
    const int* ip = pidx + p * (SPLIT * KK);
    float d0[KK], d1[KK];
    int i0[KK], i1[KK];
#pragma unroll
    for (int j = 0; j < KK; ++j) {
        d0[j] = dp[j]; d1[j] = dp[KK + j];
        i0[j] = ip[j]; i1[j] = ip[KK + j];
    }
    int* op = idx_out + p * KK;
    int ia = 0, ib = 0;
#pragma unroll
    for (int j = 0; j < KK; ++j) {
        float da = d0[ia], db = d1[ib];
        bool takeA = (da <= db);
        op[j] = takeA ? i0[ia] : i1[ib];
        ia += takeA ? 1 : 0;
        ib += takeA ? 0 : 1;
    }
}

// ---------------------------------------------------------------------------
// bf16-MFMA filter: per block 64 rows x 2048 candidates of one batch.
// score = sq_c - 2 * dot(x_row, x_cand)  (row's own sq is rank-invariant).
// Keeps per-row top-32 candidate indices -> idx32.
// ---------------------------------------------------------------------------
#define APAD 80   // LDS row stride (bf16 elems): 160 B, 16B-aligned per row
#define DPAD 65   // score-tile stride (floats)
#define LW 32     // filter list width

__global__ __launch_bounds__(256) void knn_filter_kernel(const __bf16* __restrict__ fbf,
                                                         const float* __restrict__ sq,
                                                         int* __restrict__ idx32) {
    __shared__ __align__(16) __bf16 Ab[64 * APAD];
    __shared__ __align__(16) __bf16 Bb[64 * APAD];
    __shared__ float Dt[64 * DPAD];
    __shared__ float SqC[64];
    __shared__ float Ld[64 * (LW + 1)];
    __shared__ unsigned short Li[64 * (LW + 1)];

    const int tid = threadIdx.x;
    const int b = blockIdx.x >> 5;
    const int rg = blockIdx.x & 31;
    const long pbase = (long)b * NN;
    const int row0 = rg * 64;

    // stage A (64 rows x 64 dims bf16), init lists
    {
        const int ri = tid >> 2, ch = tid & 3;
        const __bf16* src = fbf + (pbase + row0 + ri) * 64 + ch * 16;
        uint4 v0 = *(const uint4*)src;
        uint4 v1 = *(const uint4*)(src + 8);
        *(uint4*)&Ab[ri * APAD + ch * 16] = v0;
        *(uint4*)&Ab[ri * APAD + ch * 16 + 8] = v1;
        for (int i = tid; i < 64 * (LW + 1); i += 256) { Ld[i] = 3.0e38f; Li[i] = 0; }
    }
    __syncthreads();

    const int wv = tid >> 6, ln = tid & 63;
    const int n16 = ln & 15, quad = ln >> 4;
    bf16x8 af0, af1;
    {
        const __bf16* ap = &Ab[(wv * 16 + n16) * APAD + quad * 8];
        af0 = *(const bf16x8*)ap;
        af1 = *(const bf16x8*)(ap + 32);
    }

    for (int t = 0; t < NN / 64; ++t) {
        // stage B tile (64 cands x 64 dims) + sq_c
        {
            const int ci = tid >> 2, ch = tid & 3;
            const __bf16* src = fbf + (pbase + (long)t * 64 + ci) * 64 + ch * 16;
            uint4 v0 = *(const uint4*)src;
            uint4 v1 = *(const uint4*)(src + 8);
            *(uint4*)&Bb[ci * APAD + ch * 16] = v0;
            *(uint4*)&Bb[ci * APAD + ch * 16 + 8] = v1;
            if (tid < 64) SqC[tid] = sq[pbase + t * 64 + tid];
        }
        __syncthreads();   // B ready; previous selection also done

        // MFMA: this wave computes rows [wv*16, wv*16+16) x all 64 cands
#pragma unroll
        for (int ct = 0; ct < 4; ++ct) {
            const __bf16* bp = &Bb[(ct * 16 + n16) * APAD + quad * 8];
            bf16x8 bf0 = *(const bf16x8*)bp;
            bf16x8 bf1 = *(const bf16x8*)(bp + 32);
            f32x4 acc = {0.f, 0.f, 0.f, 0.f};
            acc = __builtin_amdgcn_mfma_f32_16x16x32_bf16(af0, bf0, acc, 0, 0, 0);
            acc = __builtin_amdgcn_mfma_f32_16x16x32_bf16(af1, bf1, acc, 0, 0, 0);
            const int ccol = ct * 16 + n16;
            const float sqc = SqC[ccol];
#pragma unroll
            for (int r = 0; r < 4; ++r) {
                const int rrow = wv * 16 + quad * 4 + r;
                Dt[rrow * DPAD + ccol] = fmaf(-2.0f, acc[r], sqc);
            }
        }
        __syncthreads();   // Dt ready

        // selection: thread = row, scan 64 candidates (overlaps next staging)
        if (tid < 64) {
            const int lb = tid * (LW + 1);
            float dmax = Ld[lb + LW - 1];
            for (int c = 0; c < 64; ++c) {
                float d = Dt[tid * DPAD + c];
                if (d < dmax) {
                    int pos = LW - 1;
                    while (pos > 0 && Ld[lb + pos - 1] > d) {
                        Ld[lb + pos] = Ld[lb + pos - 1];
                        Li[lb + pos] = Li[lb + pos - 1];
                        --pos;
                    }
                    Ld[lb + pos] = d;
                    Li[lb + pos] = (unsigned short)(t * 64 + c);
                    dmax = Ld[lb + LW - 1];
                }
            }
        }
    }

    if (tid < 64) {
        int* op = idx32 + (pbase + row0 + tid) * LW;
        const int lb = tid * (LW + 1);
#pragma unroll
        for (int k = 0; k < LW; ++k) op[k] = (int)Li[lb + k];
    }
}

// ---------------------------------------------------------------------------
// fp32 rescore of the 32 filtered candidates -> exact top-16 (reference
// ranking & tie semantics via lexicographic (d2, idx) rank). Wave per row.
// ---------------------------------------------------------------------------
__global__ __launch_bounds__(256) void knn_rescore_kernel(const float* __restrict__ feat,
                                                          const float* __restrict__ sq,
                                                          const int* __restrict__ idx32,
                                                          int* __restrict__ idx_out) {
    __shared__ float rowf[4][64];
    const int tid = threadIdx.x;
    const int w = tid >> 6, ln = tid & 63;
    const long p = (long)blockIdx.x * 4 + w;
    const long pbase = (p >> 11) << 11;

    if (ln < 16) *(float4*)&rowf[w][ln * 4] = *(const float4*)(feat + p * 64 + ln * 4);
    __syncthreads();

    const int c = ln & 31, h = ln >> 5;
    const int j = idx32[p * 32 + c];
    const float* cp = feat + (pbase + j) * 64 + h * 32;
    float a0 = 0.f, a1 = 0.f, a2 = 0.f, a3 = 0.f;
#pragma unroll
    for (int q = 0; q < 8; ++q) {
        float4 cv = ((const float4*)cp)[q];
        float4 rv = *(const float4*)&rowf[w][h * 32 + q * 4];
        a0 = fmaf(rv.x, cv.x, a0);
        a1 = fmaf(rv.y, cv.y, a1);
        a2 = fmaf(rv.z, cv.z, a2);
        a3 = fmaf(rv.w, cv.w, a3);
    }
    float part = (a0 + a1) + (a2 + a3);
    float dot = part + __shfl_xor(part, 32);
    float score = fmaf(-2.0f, dot, sq[pbase + j]);

    int rank = 0;
#pragma unroll
    for (int m = 0; m < 32; ++m) {
        float dm = __shfl(score, m);
        int jm = __shfl(j, m);
        rank += (dm < score || (dm == score && jm < j)) ? 1 : 0;
    }
    if (h == 0 && rank < KK) idx_out[p * KK + rank] = j;
}

// ---------------------------------------------------------------------------
// P[p][h] = b1[h] + sum_d f[p][d] * (w1[d][h] - w1[D+d][h])
// Q[p][h] =         sum_d f[p][d] *  w1[D+d][h]
// ---------------------------------------------------------------------------
template <int D>
__global__ __launch_bounds__(256) void pq_kernel(const float* __restrict__ feat,
                                                 const float* __restrict__ w1,
                                                 const float* __restrict__ b1,
                                                 float* __restrict__ P,
                                                 float* __restrict__ Q) {
    const int tid = threadIdx.x;
    const int h = tid & 63;
    const int pl = tid >> 6;
    const long p = (long)blockIdx.x * 4 + pl;   // p < BN
    const float* fp = feat + p * D;
    float accp = 0.f, accq = 0.f;
#pragma unroll
    for (int d = 0; d < D; ++d) {
        float fv = fp[d];
        float wa = w1[d * HH + h];
        float wb = w1[(D + d) * HH + h];
        accp = fmaf(fv, wa - wb, accp);
        accq = fmaf(fv, wb, accq);
    }
    P[p * HH + h] = accp + b1[h];
    Q[p * HH + h] = accq;
}

// ---------------------------------------------------------------------------
// R[p] = (1/K) sum_k relu(P[p] + Q[j_k]);  out[p] = R[p] @ wo + bo
// ---------------------------------------------------------------------------
__global__ __launch_bounds__(256) void gather_mlp_kernel(const float* __restrict__ P,
                                                         const float* __restrict__ Q,
                                                         const int* __restrict__ idx,
                                                         const float* __restrict__ wo,
                                                         const float* __restrict__ bo,
                                                         float* __restrict__ out) {
    __shared__ float Rl[4][HH];
    const int tid = threadIdx.x;
    const int h = tid & 63;
    const int pl = tid >> 6;
    const long p = (long)blockIdx.x * 4 + pl;
    const long bbase = (p >> 11) << 11;    // batch base point index
    const float Pv = P[p * HH + h];
    const int* ip = idx + p * KK;
    float acc = 0.f;
#pragma unroll
    for (int k = 0; k < KK; ++k) {
        int j = ip[k];
        float qv = Q[(bbase + j) * HH + h];
        acc += fmaxf(Pv + qv, 0.f);
    }
    acc *= (1.f / KK);
    Rl[pl][h] = acc;
    __syncthreads();
    float o = bo[h];
#pragma unroll
    for (int l = 0; l < HH; ++l) o = fmaf(Rl[pl][l], wo[l * HH + h], o);
    out[p * HH + h] = o;
}

// ---------------------------------------------------------------------------
// g[b] = mean_n feat[b,n,:];  out[b] = relu(g@fw1+fb1)@fw2+fb2
// ---------------------------------------------------------------------------
__global__ __launch_bounds__(256) void pool_head_kernel(const float* __restrict__ feat,
                                                        const float* __restrict__ fw1,
                                                        const float* __restrict__ fb1,
                                                        const float* __restrict__ fw2,
                                                        const float* __restrict__ fb2,
                                                        float* __restrict__ out) {
    __shared__ float part[4][HH];
    __shared__ float g[HH];
    __shared__ float tl[HH];
    const int b = blockIdx.x;
    const int tid = threadIdx.x;
    const int h = tid & 63;
    const int ch = tid >> 6;
    float s = 0.f;
    const float* fp = feat + ((long)b * NN + ch * 512) * HH + h;
    for (int n = 0; n < 512; ++n) s += fp[(long)n * HH];
    part[ch][h] = s;
    __syncthreads();
    if (tid < HH) g[h] = (part[0][h] + part[1][h] + part[2][h] + part[3][h]) * (1.f / NN);
    __syncthreads();
    if (tid < HH) {
        float a = fb1[h];
#pragma unroll
        for (int l = 0; l < HH; ++l) a = fmaf(g[l], fw1[l * HH + h], a);
        tl[h] = fmaxf(a, 0.f);
    }
    __syncthreads();
    if (tid < OUTC) {
        float o = fb2[tid];
#pragma unroll
        for (int l = 0; l < HH; ++l) o = fmaf(tl[l], fw2[l * OUTC + tid], o);
        out[(long)b * OUTC + tid] = o;
    }
}

// ---------------------------------------------------------------------------
extern "C" void kernel_launch(void* const* d_in, const int* in_sizes, int n_in,
                              void* d_out, int out_size, void* d_ws, size_t ws_size,
                              hipStream_t stream) {
    const float* x    = (const float*)d_in[0];
    const float* w1_0 = (const float*)d_in[1];
    const float* b1_0 = (const float*)d_in[2];
    const float* wo_0 = (const float*)d_in[3];
    const float* bo_0 = (const float*)d_in[4];
    const float* w1_1 = (const float*)d_in[5];
    const float* b1_1 = (const float*)d_in[6];
    const float* wo_1 = (const float*)d_in[7];
    const float* bo_1 = (const float*)d_in[8];
    const float* w1_2 = (const float*)d_in[9];
    const float* b1_2 = (const float*)d_in[10];
    const float* wo_2 = (const float*)d_in[11];
    const float* bo_2 = (const float*)d_in[12];
    const float* fw1  = (const float*)d_in[13];
    const float* fb1  = (const float*)d_in[14];
    const float* fw2  = (const float*)d_in[15];
    const float* fb2  = (const float*)d_in[16];
    float* out = (float*)d_out;

    // workspace layout (floats)
    float* featA = (float*)d_ws;
    float* featB = featA + (long)BN * HH;
    float* Pb    = featB + (long)BN * HH;
    float* Qb    = Pb + (long)BN * HH;
    float* sqb   = Qb + (long)BN * HH;
    int*   idxb  = (int*)(sqb + BN);

    // regions reused before pq_kernel writes Pb/Qb:
    float*  pdist = Pb;                 // layer-0 partial dists
    int*    pidx  = (int*)Qb;           // layer-0 partial idx
    int*    idx32 = (int*)Pb;           // filter output (BN x 32)
    __bf16* fbf   = (__bf16*)Qb;        // bf16 features (BN x 64)

    // ---- layer 0 (D=3) ----
    sq_kernel<3><<<BN / 256, 256, 0, stream>>>(x, sqb);
    knn3_part_kernel<<<256 * SPLIT, 256, 0, stream>>>(x, sqb, pdist, pidx);
    knn_merge_kernel<<<BN / 256, 256, 0, stream>>>(pdist, pidx, idxb);
    pq_kernel<3><<<BN / 4, 256, 0, stream>>>(x, w1_0, b1_0, Pb, Qb);
    gather_mlp_kernel<<<BN / 4, 256, 0, stream>>>(Pb, Qb, idxb, wo_0, bo_0, featA);

    // ---- layer 1 (D=64) ----
    sq_kernel<64><<<BN / 256, 256, 0, stream>>>(featA, sqb);
    tobf16_kernel<<<BN * HH / 2048, 256, 0, stream>>>(featA, fbf);
    knn_filter_kernel<<<BB * 32, 256, 0, stream>>>(fbf, sqb, idx32);
    knn_rescore_kernel<<<BN / 4, 256, 0, stream>>>(featA, sqb, idx32, idxb);
    pq_kernel<64><<<BN / 4, 256, 0, stream>>>(featA, w1_1, b1_1, Pb, Qb);
    gather_mlp_kernel<<<BN / 4, 256, 0, stream>>>(Pb, Qb, idxb, wo_1, bo_1, featB);

    // ---- layer 2 (D=64) ----
    sq_kernel<64><<<BN / 256, 256, 0, stream>>>(featB, sqb);
    tobf16_kernel<<<BN * HH / 2048, 256, 0, stream>>>(featB, fbf);
    knn_filter_kernel<<<BB * 32, 256, 0, stream>>>(fbf, sqb, idx32);
    knn_rescore_kernel<<<BN / 4, 256, 0, stream>>>(featB, sqb, idx32, idxb);
    pq_kernel<64><<<BN / 4, 256, 0, stream>>>(featB, w1_2, b1_2, Pb, Qb);
    gather_mlp_kernel<<<BN / 4, 256, 0, stream>>>(Pb, Qb, idxb, wo_2, bo_2, featA);

    // ---- pool + head ----
    pool_head_kernel<<<BB, 256, 0, stream>>>(featA, fw1, fb1, fw2, fb2, out);
}

// Round 4
// 1859.484 us; speedup vs baseline: 7.7130x; 7.7130x over previous
//
#include <hip/hip_runtime.h>

// Problem constants
#define BB 32
#define NN 2048
#define FF 3
#define HH 64
#define OUTC 128
#define KK 16
#define BN (BB * NN)   // 65536 points

#define SPLIT 2
#define CSZ3 (NN / SPLIT)  // 1024 candidates per knn3 partial scan

typedef __attribute__((ext_vector_type(8))) __bf16 bf16x8;
typedef __attribute__((ext_vector_type(4))) float f32x4;

// ---------------------------------------------------------------------------
// sq[p] = sum_d feat[p][d]^2
// ---------------------------------------------------------------------------
template <int D>
__global__ __launch_bounds__(256) void sq_kernel(const float* __restrict__ f,
                                                 float* __restrict__ sqo) {
    long p = (long)blockIdx.x * 256 + threadIdx.x;   // p < BN
    const float* fp = f + p * D;
    float s = 0.f;
#pragma unroll
    for (int d = 0; d < D; ++d) s = fmaf(fp[d], fp[d], s);
    sqo[p] = s;
}

// ---------------------------------------------------------------------------
// fp32 -> bf16 conversion (RNE). 8 elems per thread.
// ---------------------------------------------------------------------------
__global__ __launch_bounds__(256) void tobf16_kernel(const float* __restrict__ f,
                                                     __bf16* __restrict__ o) {
    long base = ((long)blockIdx.x * 256 + threadIdx.x) * 8;
    const float4* fp = (const float4*)(f + base);
    float4 v0 = fp[0], v1 = fp[1];
    unsigned short us[8];
    us[0] = __builtin_bit_cast(unsigned short, (__bf16)v0.x);
    us[1] = __builtin_bit_cast(unsigned short, (__bf16)v0.y);
    us[2] = __builtin_bit_cast(unsigned short, (__bf16)v0.z);
    us[3] = __builtin_bit_cast(unsigned short, (__bf16)v0.w);
    us[4] = __builtin_bit_cast(unsigned short, (__bf16)v1.x);
    us[5] = __builtin_bit_cast(unsigned short, (__bf16)v1.y);
    us[6] = __builtin_bit_cast(unsigned short, (__bf16)v1.z);
    us[7] = __builtin_bit_cast(unsigned short, (__bf16)v1.w);
    *(uint4*)(o + base) = *(const uint4*)us;
}

// ---------------------------------------------------------------------------
// kNN partial scan for D=3 (layer 0), candidate-split 2-way.
// ---------------------------------------------------------------------------
__global__ __launch_bounds__(256) void knn3_part_kernel(const float* __restrict__ x,
                                                        const float* __restrict__ sq,
                                                        float* __restrict__ pdist,
                                                        int* __restrict__ pidx) {
    __shared__ float4 lds_c[256];
    const int s = blockIdx.x & (SPLIT - 1);
    const int rbb = blockIdx.x / SPLIT;
    const int b = rbb >> 3;
    const int rb = rbb & 7;
    const int tid = threadIdx.x;
    const int row = rb * 256 + tid;
    const long pbase = (long)b * NN;

    const float* rp = x + (pbase + row) * 3;
    const float xr0 = rp[0], xr1 = rp[1], xr2 = rp[2];
    const float sqr = sq[pbase + row];

    float dist[KK];
    int idx[KK];
#pragma unroll
    for (int j = 0; j < KK; ++j) { dist[j] = 3.0e38f; idx[j] = 0; }

    for (int t = s * (CSZ3 / 256); t < (s + 1) * (CSZ3 / 256); ++t) {
        __syncthreads();
        {
            const int m = t * 256 + tid;
            const float* cp = x + (pbase + m) * 3;
            lds_c[tid] = make_float4(cp[0], cp[1], cp[2], sq[pbase + m]);
        }
        __syncthreads();
        for (int c = 0; c < 256; ++c) {
            float4 v = lds_c[c];
            float acc = 0.f;
            acc = fmaf(xr0, v.x, acc);
            acc = fmaf(xr1, v.y, acc);
            acc = fmaf(xr2, v.z, acc);
            float d2 = fmaf(-2.0f, acc, sqr + v.w);
            int m = t * 256 + c;
            if (d2 < dist[KK - 1]) {
                float cd = d2; int ci = m;
#pragma unroll
                for (int j = 0; j < KK; ++j) {
                    bool sw = cd < dist[j];
                    float td = dist[j]; int ti = idx[j];
                    dist[j] = sw ? cd : td; idx[j] = sw ? ci : ti;
                    cd = sw ? td : cd; ci = sw ? ti : ci;
                }
            }
        }
    }
    float* dp = pdist + ((pbase + row) * SPLIT + s) * KK;
    int* ip = pidx + ((pbase + row) * SPLIT + s) * KK;
#pragma unroll
    for (int j = 0; j < KK; ++j) { dp[j] = dist[j]; ip[j] = idx[j]; }
}

// ---------------------------------------------------------------------------
// Merge SPLIT sorted partial top-16 lists -> final top-16 indices per row.
// ---------------------------------------------------------------------------
__global__ __launch_bounds__(256) void knn_merge_kernel(const float* __restrict__ pdist,
                                                        const int* __restrict__ pidx,
                                                        int* __restrict__ idx_out) {
    long p = (long)blockIdx.x * 256 + threadIdx.x;
    const float* dp = pdist + p * (SPLIT * KK);
    const int* ip = pidx + p * (SPLIT * KK);
    float d0[KK], d1[KK];
    int i0[KK], i1[KK];
#pragma unroll
    for (int j = 0; j < KK; ++j) {
        d0[j] = dp[j]; d1[j] = dp[KK + j];
        i0[j] = ip[j]; i1[j] = ip[KK + j];
    }
    int* op = idx_out + p * KK;
    int ia = 0, ib = 0;
#pragma unroll
    for (int j = 0; j < KK; ++j) {
        float da = d0[ia], db = d1[ib];
        bool takeA = (da <= db);
        op[j] = takeA ? i0[ia] : i1[ib];
        ia += takeA ? 1 : 0;
        ib += takeA ? 0 : 1;
    }
}

// ---------------------------------------------------------------------------
// bf16-MFMA filter v2: block = 64 rows x 2048 candidates of one batch.
// score = sq_c - 2 * dot(x_row, x_cand)  (row's own sq is rank-invariant).
// Selection: thread = (row, slot of 4); per-thread REGISTER sorted top-16
// over its 512-candidate subset (cands with (c mod 64)/16 == slot).
// Union of the 4 subsets' top-16 provably contains the row's true top-16.
// Output: idx64[row][64] = the 4 concatenated lists (unordered set is fine —
// rescore re-ranks exactly in fp32).
// ---------------------------------------------------------------------------
#define APAD 80   // LDS row stride (bf16 elems): 160 B, 16B-aligned per row
#define DPAD 65   // score-tile stride (floats); 2-way bank alias only (free)

__global__ __launch_bounds__(256) void knn_filter_kernel(const __bf16* __restrict__ fbf,
                                                         const float* __restrict__ sq,
                                                         int* __restrict__ idx64) {
    __shared__ __align__(16) __bf16 Ab[64 * APAD];
    __shared__ __align__(16) __bf16 Bb[64 * APAD];
    __shared__ float Dt[64 * DPAD];
    __shared__ float SqC[64];

    const int tid = threadIdx.x;
    const int b = blockIdx.x >> 5;
    const int rg = blockIdx.x & 31;
    const long pbase = (long)b * NN;
    const int row0 = rg * 64;

    // stage A (64 rows x 64 dims bf16)
    {
        const int ri = tid >> 2, ch = tid & 3;
        const __bf16* src = fbf + (pbase + row0 + ri) * 64 + ch * 16;
        uint4 v0 = *(const uint4*)src;
        uint4 v1 = *(const uint4*)(src + 8);
        *(uint4*)&Ab[ri * APAD + ch * 16] = v0;
        *(uint4*)&Ab[ri * APAD + ch * 16 + 8] = v1;
    }
    __syncthreads();

    const int wv = tid >> 6, ln = tid & 63;
    const int n16 = ln & 15, quad = ln >> 4;
    bf16x8 af0, af1;
    {
        const __bf16* ap = &Ab[(wv * 16 + n16) * APAD + quad * 8];
        af0 = *(const bf16x8*)ap;
        af1 = *(const bf16x8*)(ap + 32);
    }

    // per-thread selection state: row r = tid>>2, slot = tid&3
    const int r = tid >> 2, slot = tid & 3;
    float ld[KK];
    int li[KK];
#pragma unroll
    for (int j = 0; j < KK; ++j) { ld[j] = 3.0e38f; li[j] = 0; }

    for (int t = 0; t < NN / 64; ++t) {
        // stage B tile (64 cands x 64 dims) + sq_c
        {
            const int ci = tid >> 2, ch = tid & 3;
            const __bf16* src = fbf + (pbase + (long)t * 64 + ci) * 64 + ch * 16;
            uint4 v0 = *(const uint4*)src;
            uint4 v1 = *(const uint4*)(src + 8);
            *(uint4*)&Bb[ci * APAD + ch * 16] = v0;
            *(uint4*)&Bb[ci * APAD + ch * 16 + 8] = v1;
            if (tid < 64) SqC[tid] = sq[pbase + t * 64 + tid];
        }
        __syncthreads();   // B/SqC ready; previous tile's selection done

        // MFMA: wave wv computes rows [wv*16, wv*16+16) x all 64 cands
#pragma unroll
        for (int ct = 0; ct < 4; ++ct) {
            const __bf16* bp = &Bb[(ct * 16 + n16) * APAD + quad * 8];
            bf16x8 bf0 = *(const bf16x8*)bp;
            bf16x8 bf1 = *(const bf16x8*)(bp + 32);
            f32x4 acc = {0.f, 0.f, 0.f, 0.f};
            acc = __builtin_amdgcn_mfma_f32_16x16x32_bf16(af0, bf0, acc, 0, 0, 0);
            acc = __builtin_amdgcn_mfma_f32_16x16x32_bf16(af1, bf1, acc, 0, 0, 0);
            const int ccol = ct * 16 + n16;
            const float sqc = SqC[ccol];
#pragma unroll
            for (int rr = 0; rr < 4; ++rr) {
                const int rrow = wv * 16 + quad * 4 + rr;
                Dt[rrow * DPAD + ccol] = fmaf(-2.0f, acc[rr], sqc);
            }
        }
        __syncthreads();   // Dt ready

        // selection: 256 threads, register carry-insert into sorted top-16
        const float* dr = &Dt[r * DPAD + slot * 16];
        const int mbase = t * 64 + slot * 16;
#pragma unroll
        for (int jj = 0; jj < 16; ++jj) {
            float d = dr[jj];
            if (d < ld[KK - 1]) {
                float cd = d; int ci = mbase + jj;
#pragma unroll
                for (int sI = 0; sI < KK; ++sI) {
                    bool sw = cd < ld[sI];
                    float td = ld[sI]; int ti = li[sI];
                    ld[sI] = sw ? cd : td; li[sI] = sw ? ci : ti;
                    cd = sw ? td : cd; ci = sw ? ti : ci;
                }
            }
        }
    }

    // write the 4 lists concatenated: idx64[row][slot*16 + j]
    {
        int* op = idx64 + (pbase + row0 + r) * 64 + slot * 16;
        int4 v;
#pragma unroll
        for (int q = 0; q < 4; ++q) {
            v.x = li[4 * q + 0]; v.y = li[4 * q + 1];
            v.z = li[4 * q + 2]; v.w = li[4 * q + 3];
            ((int4*)op)[q] = v;
        }
    }
}

// ---------------------------------------------------------------------------
// fp32 rescore of the 64 filtered candidates -> exact top-16 (reference
// ranking & tie semantics via lexicographic (d2, idx) rank). Wave per row;
// lane = candidate.
// ---------------------------------------------------------------------------
__global__ __launch_bounds__(256) void knn_rescore_kernel(const float* __restrict__ feat,
                                                          const float* __restrict__ sq,
                                                          const int* __restrict__ idx64,
                                                          int* __restrict__ idx_out) {
    __shared__ float rowf[4][64];
    const int tid = threadIdx.x;
    const int w = tid >> 6, ln = tid & 63;
    const long p = (long)blockIdx.x * 4 + w;
    const long pbase = (p >> 11) << 11;

    if (ln < 16) *(float4*)&rowf[w][ln * 4] = *(const float4*)(feat + p * 64 + ln * 4);
    __syncthreads();

    const int j = idx64[p * 64 + ln];
    const float* cp = feat + (pbase + j) * 64;
    float a0 = 0.f, a1 = 0.f, a2 = 0.f, a3 = 0.f;
#pragma unroll
    for (int q = 0; q < 16; ++q) {
        float4 cv = ((const float4*)cp)[q];
        float4 rv = *(const float4*)&rowf[w][q * 4];
        a0 = fmaf(rv.x, cv.x, a0);
        a1 = fmaf(rv.y, cv.y, a1);
        a2 = fmaf(rv.z, cv.z, a2);
        a3 = fmaf(rv.w, cv.w, a3);
    }
    float dot = (a0 + a1) + (a2 + a3);
    float score = fmaf(-2.0f, dot, sq[pbase + j]);

    int rank = 0;
#pragma unroll
    for (int m = 0; m < 64; ++m) {
        float dm = __shfl(score, m);
        int jm = __shfl(j, m);
        rank += (dm < score || (dm == score && jm < j)) ? 1 : 0;
    }
    if (rank < KK) idx_out[p * KK + rank] = j;
}

// ---------------------------------------------------------------------------
// P[p][h] = b1[h] + sum_d f[p][d] * (w1[d][h] - w1[D+d][h])
// Q[p][h] =         sum_d f[p][d] *  w1[D+d][h]
// ---------------------------------------------------------------------------
template <int D>
__global__ __launch_bounds__(256) void pq_kernel(const float* __restrict__ feat,
                                                 const float* __restrict__ w1,
                                                 const float* __restrict__ b1,
                                                 float* __restrict__ P,
                                                 float* __restrict__ Q) {
    const int tid = threadIdx.x;
    const int h = tid & 63;
    const int pl = tid >> 6;
    const long p = (long)blockIdx.x * 4 + pl;   // p < BN
    const float* fp = feat + p * D;
    float accp = 0.f, accq = 0.f;
#pragma unroll
    for (int d = 0; d < D; ++d) {
        float fv = fp[d];
        float wa = w1[d * HH + h];
        float wb = w1[(D + d) * HH + h];
        accp = fmaf(fv, wa - wb, accp);
        accq = fmaf(fv, wb, accq);
    }
    P[p * HH + h] = accp + b1[h];
    Q[p * HH + h] = accq;
}

// ---------------------------------------------------------------------------
// R[p] = (1/K) sum_k relu(P[p] + Q[j_k]);  out[p] = R[p] @ wo + bo
// ---------------------------------------------------------------------------
__global__ __launch_bounds__(256) void gather_mlp_kernel(const float* __restrict__ P,
                                                         const float* __restrict__ Q,
                                                         const int* __restrict__ idx,
                                                         const float* __restrict__ wo,
                                                         const float* __restrict__ bo,
                                                         float* __restrict__ out) {
    __shared__ float Rl[4][HH];
    const int tid = threadIdx.x;
    const int h = tid & 63;
    const int pl = tid >> 6;
    const long p = (long)blockIdx.x * 4 + pl;
    const long bbase = (p >> 11) << 11;    // batch base point index
    const float Pv = P[p * HH + h];
    const int* ip = idx + p * KK;
    float acc = 0.f;
#pragma unroll
    for (int k = 0; k < KK; ++k) {
        int j = ip[k];
        float qv = Q[(bbase + j) * HH + h];
        acc += fmaxf(Pv + qv, 0.f);
    }
    acc *= (1.f / KK);
    Rl[pl][h] = acc;
    __syncthreads();
    float o = bo[h];
#pragma unroll
    for (int l = 0; l < HH; ++l) o = fmaf(Rl[pl][l], wo[l * HH + h], o);
    out[p * HH + h] = o;
}

// ---------------------------------------------------------------------------
// g[b] = mean_n feat[b,n,:];  out[b] = relu(g@fw1+fb1)@fw2+fb2
// ---------------------------------------------------------------------------
__global__ __launch_bounds__(256) void pool_head_kernel(const float* __restrict__ feat,
                                                        const float* __restrict__ fw1,
                                                        const float* __restrict__ fb1,
                                                        const float* __restrict__ fw2,
                                                        const float* __restrict__ fb2,
                                                        float* __restrict__ out) {
    __shared__ float part[4][HH];
    __shared__ float g[HH];
    __shared__ float tl[HH];
    const int b = blockIdx.x;
    const int tid = threadIdx.x;
    const int h = tid & 63;
    const int ch = tid >> 6;
    float s = 0.f;
    const float* fp = feat + ((long)b * NN + ch * 512) * HH + h;
    for (int n = 0; n < 512; ++n) s += fp[(long)n * HH];
    part[ch][h] = s;
    __syncthreads();
    if (tid < HH) g[h] = (part[0][h] + part[1][h] + part[2][h] + part[3][h]) * (1.f / NN);
    __syncthreads();
    if (tid < HH) {
        float a = fb1[h];
#pragma unroll
        for (int l = 0; l < HH; ++l) a = fmaf(g[l], fw1[l * HH + h], a);
        tl[h] = fmaxf(a, 0.f);
    }
    __syncthreads();
    if (tid < OUTC) {
        float o = fb2[tid];
#pragma unroll
        for (int l = 0; l < HH; ++l) o = fmaf(tl[l], fw2[l * OUTC + tid], o);
        out[(long)b * OUTC + tid] = o;
    }
}

// ---------------------------------------------------------------------------
extern "C" void kernel_launch(void* const* d_in, const int* in_sizes, int n_in,
                              void* d_out, int out_size, void* d_ws, size_t ws_size,
                              hipStream_t stream) {
    const float* x    = (const float*)d_in[0];
    const float* w1_0 = (const float*)d_in[1];
    const float* b1_0 = (const float*)d_in[2];
    const float* wo_0 = (const float*)d_in[3];
    const float* bo_0 = (const float*)d_in[4];
    const float* w1_1 = (const float*)d_in[5];
    const float* b1_1 = (const float*)d_in[6];
    const float* wo_1 = (const float*)d_in[7];
    const float* bo_1 = (const float*)d_in[8];
    const float* w1_2 = (const float*)d_in[9];
    const float* b1_2 = (const float*)d_in[10];
    const float* wo_2 = (const float*)d_in[11];
    const float* bo_2 = (const float*)d_in[12];
    const float* fw1  = (const float*)d_in[13];
    const float* fb1  = (const float*)d_in[14];
    const float* fw2  = (const float*)d_in[15];
    const float* fb2  = (const float*)d_in[16];
    float* out = (float*)d_out;

    // workspace layout (floats)
    float* featA = (float*)d_ws;
    float* featB = featA + (long)BN * HH;
    float* Pb    = featB + (long)BN * HH;
    float* Qb    = Pb + (long)BN * HH;
    float* sqb   = Qb + (long)BN * HH;
    int*   idxb  = (int*)(sqb + BN);

    // regions reused before pq_kernel writes Pb/Qb:
    float*  pdist = Pb;                 // layer-0 partial dists
    int*    pidx  = (int*)Qb;           // layer-0 partial idx
    int*    idx64 = (int*)Pb;           // filter output (BN x 64)
    __bf16* fbf   = (__bf16*)Qb;        // bf16 features (BN x 64)

    // ---- layer 0 (D=3) ----
    sq_kernel<3><<<BN / 256, 256, 0, stream>>>(x, sqb);
    knn3_part_kernel<<<256 * SPLIT, 256, 0, stream>>>(x, sqb, pdist, pidx);
    knn_merge_kernel<<<BN / 256, 256, 0, stream>>>(pdist, pidx, idxb);
    pq_kernel<3><<<BN / 4, 256, 0, stream>>>(x, w1_0, b1_0, Pb, Qb);
    gather_mlp_kernel<<<BN / 4, 256, 0, stream>>>(Pb, Qb, idxb, wo_0, bo_0, featA);

    // ---- layer 1 (D=64) ----
    sq_kernel<64><<<BN / 256, 256, 0, stream>>>(featA, sqb);
    tobf16_kernel<<<BN * HH / 2048, 256, 0, stream>>>(featA, fbf);
    knn_filter_kernel<<<BB * 32, 256, 0, stream>>>(fbf, sqb, idx64);
    knn_rescore_kernel<<<BN / 4, 256, 0, stream>>>(featA, sqb, idx64, idxb);
    pq_kernel<64><<<BN / 4, 256, 0, stream>>>(featA, w1_1, b1_1, Pb, Qb);
    gather_mlp_kernel<<<BN / 4, 256, 0, stream>>>(Pb, Qb, idxb, wo_1, bo_1, featB);

    // ---- layer 2 (D=64) ----
    sq_kernel<64><<<BN / 256, 256, 0, stream>>>(featB, sqb);
    tobf16_kernel<<<BN * HH / 2048, 256, 0, stream>>>(featB, fbf);
    knn_filter_kernel<<<BB * 32, 256, 0, stream>>>(fbf, sqb, idx64);
    knn_rescore_kernel<<<BN / 4, 256, 0, stream>>>(featB, sqb, idx64, idxb);
    pq_kernel<64><<<BN / 4, 256, 0, stream>>>(featB, w1_2, b1_2, Pb, Qb);
    gather_mlp_kernel<<<BN / 4, 256, 0, stream>>>(Pb, Qb, idxb, wo_2, bo_2, featA);

    // ---- pool + head ----
    pool_head_kernel<<<BB, 256, 0, stream>>>(featA, fw1, fb1, fw2, fb2, out);
}

// Round 5
// 1089.776 us; speedup vs baseline: 13.1606x; 1.7063x over previous
//
#include <hip/hip_runtime.h>

// Problem constants
#define BB 32
#define NN 2048
#define FF 3
#define HH 64
#define OUTC 128
#define KK 16
#define BN (BB * NN)   // 65536 points

typedef __attribute__((ext_vector_type(8))) __bf16 bf16x8;
typedef __attribute__((ext_vector_type(4))) float f32x4;

// Pack d2 + candidate index into one sortable u32:
// high 21 bits = monotone(float d2) truncated, low 11 bits = idx (NN=2^11).
__device__ __forceinline__ unsigned int packkey(float d2, unsigned int m) {
    unsigned int bb = __builtin_bit_cast(unsigned int, d2);
    unsigned int msk = (unsigned int)((int)bb >> 31);
    unsigned int srt = bb ^ (msk | 0x80000000u);
    return (srt & 0xFFFFF800u) | m;
}

// Branchless sorted carry-insert (ascending): 2 inst/slot (v_min/v_max).
#define INSERT16(keys, cand)                                     \
    {                                                            \
        unsigned int ck = (cand);                                \
        _Pragma("unroll") for (int sI = 0; sI < KK; ++sI) {      \
            unsigned int lo = keys[sI] < ck ? keys[sI] : ck;     \
            unsigned int hi = keys[sI] < ck ? ck : keys[sI];     \
            keys[sI] = lo; ck = hi;                              \
        }                                                        \
    }

// ---------------------------------------------------------------------------
// sq[p] = sum_d feat[p][d]^2
// ---------------------------------------------------------------------------
template <int D>
__global__ __launch_bounds__(256) void sq_kernel(const float* __restrict__ f,
                                                 float* __restrict__ sqo) {
    long p = (long)blockIdx.x * 256 + threadIdx.x;   // p < BN
    const float* fp = f + p * D;
    float s = 0.f;
#pragma unroll
    for (int d = 0; d < D; ++d) s = fmaf(fp[d], fp[d], s);
    sqo[p] = s;
}

// ---------------------------------------------------------------------------
// fp32 -> bf16 conversion (RNE). 8 elems per thread.
// ---------------------------------------------------------------------------
__global__ __launch_bounds__(256) void tobf16_kernel(const float* __restrict__ f,
                                                     __bf16* __restrict__ o) {
    long base = ((long)blockIdx.x * 256 + threadIdx.x) * 8;
    const float4* fp = (const float4*)(f + base);
    float4 v0 = fp[0], v1 = fp[1];
    unsigned short us[8];
    us[0] = __builtin_bit_cast(unsigned short, (__bf16)v0.x);
    us[1] = __builtin_bit_cast(unsigned short, (__bf16)v0.y);
    us[2] = __builtin_bit_cast(unsigned short, (__bf16)v0.z);
    us[3] = __builtin_bit_cast(unsigned short, (__bf16)v0.w);
    us[4] = __builtin_bit_cast(unsigned short, (__bf16)v1.x);
    us[5] = __builtin_bit_cast(unsigned short, (__bf16)v1.y);
    us[6] = __builtin_bit_cast(unsigned short, (__bf16)v1.z);
    us[7] = __builtin_bit_cast(unsigned short, (__bf16)v1.w);
    *(uint4*)(o + base) = *(const uint4*)us;
}

// ---------------------------------------------------------------------------
// Layer-0 kNN filter (D=3, fp32 scores): block = 64 rows x 2048 cands.
// Thread = (row, slot of 4); slot scans 64 cands per 256-tile (disjoint).
// Per-thread register top-16 of packed u32 keys, branchless always-insert.
// Pairwise bitonic merge 4x16 -> two half-union top-16 sets = 32 cands.
// ---------------------------------------------------------------------------
__global__ __launch_bounds__(256) void knn3_filter_kernel(const float* __restrict__ x,
                                                          const float* __restrict__ sq,
                                                          int* __restrict__ idx32) {
    __shared__ float4 lds_c[256];
    __shared__ unsigned int Km[64 * 68];
    const int tid = threadIdx.x;
    const int b = blockIdx.x >> 5;
    const int rg = blockIdx.x & 31;
    const long pbase = (long)b * NN;
    const int r = tid >> 2, slot = tid & 3;
    const int row = rg * 64 + r;

    const float* rp = x + (pbase + row) * 3;
    const float xr0 = rp[0], xr1 = rp[1], xr2 = rp[2];

    unsigned int keys[KK];
#pragma unroll
    for (int j = 0; j < KK; ++j) keys[j] = 0xFFFFFFFFu;

    for (int t = 0; t < NN / 256; ++t) {
        __syncthreads();
        {
            const int m = t * 256 + tid;
            const float* cp = x + (pbase + m) * 3;
            lds_c[tid] = make_float4(cp[0], cp[1], cp[2], sq[pbase + m]);
        }
        __syncthreads();
        const int cbase = slot * 64;
#pragma unroll 4
        for (int cc = 0; cc < 64; ++cc) {
            float4 v = lds_c[cbase + cc];
            float dot = fmaf(xr0, v.x, fmaf(xr1, v.y, xr2 * v.z));
            float d2 = fmaf(-2.0f, dot, v.w);   // sq_row dropped (rank-invariant)
            INSERT16(keys, packkey(d2, (unsigned int)(t * 256 + cbase + cc)));
        }
    }

    // merge: 4 sorted lists -> 2 x (lowest-16 of half-union) = 32 cands
    {
        uint4* kw = (uint4*)&Km[r * 68 + slot * 16];
#pragma unroll
        for (int q = 0; q < 4; ++q)
            kw[q] = make_uint4(keys[4 * q], keys[4 * q + 1], keys[4 * q + 2], keys[4 * q + 3]);
    }
    __syncthreads();
    if (slot < 2) {
        const unsigned int* k0 = &Km[r * 68 + slot * 32];
        const unsigned int* k1 = k0 + 16;
        int mo[16];
#pragma unroll
        for (int j = 0; j < 16; ++j) {
            unsigned int a = k0[j], bv = k1[15 - j];
            mo[j] = (int)((a < bv ? a : bv) & 0x7FFu);
        }
        int4* op = (int4*)(idx32 + (pbase + row) * 32 + slot * 16);
#pragma unroll
        for (int q = 0; q < 4; ++q)
            op[q] = make_int4(mo[4 * q], mo[4 * q + 1], mo[4 * q + 2], mo[4 * q + 3]);
    }
}

// ---------------------------------------------------------------------------
// bf16-MFMA filter (D=64): block = 64 rows x 2048 cands of one batch.
// MFMA phase packs keys directly into Dt; selection = register always-insert.
// ---------------------------------------------------------------------------
#define APAD 80   // LDS row stride (bf16 elems)
#define DPAD 68   // key-tile stride (u32); keeps 16B alignment for b128 reads

__global__ __launch_bounds__(256) void knn_filter_kernel(const __bf16* __restrict__ fbf,
                                                         const float* __restrict__ sq,
                                                         int* __restrict__ idx32) {
    __shared__ __align__(16) __bf16 Ab[64 * APAD];
    __shared__ __align__(16) __bf16 Bb[64 * APAD];
    __shared__ __align__(16) unsigned int Dt[64 * DPAD];
    __shared__ float SqC[64];

    const int tid = threadIdx.x;
    const int b = blockIdx.x >> 5;
    const int rg = blockIdx.x & 31;
    const long pbase = (long)b * NN;
    const int row0 = rg * 64;

    // stage A (64 rows x 64 dims bf16)
    {
        const int ri = tid >> 2, ch = tid & 3;
        const __bf16* src = fbf + (pbase + row0 + ri) * 64 + ch * 16;
        uint4 v0 = *(const uint4*)src;
        uint4 v1 = *(const uint4*)(src + 8);
        *(uint4*)&Ab[ri * APAD + ch * 16] = v0;
        *(uint4*)&Ab[ri * APAD + ch * 16 + 8] = v1;
    }
    __syncthreads();

    const int wv = tid >> 6, ln = tid & 63;
    const int n16 = ln & 15, quad = ln >> 4;
    bf16x8 af0, af1;
    {
        const __bf16* ap = &Ab[(wv * 16 + n16) * APAD + quad * 8];
        af0 = *(const bf16x8*)ap;
        af1 = *(const bf16x8*)(ap + 32);
    }

    const int r = tid >> 2, slot = tid & 3;
    unsigned int keys[KK];
#pragma unroll
    for (int j = 0; j < KK; ++j) keys[j] = 0xFFFFFFFFu;

    for (int t = 0; t < NN / 64; ++t) {
        // stage B tile (64 cands x 64 dims) + sq_c
        {
            const int ci = tid >> 2, ch = tid & 3;
            const __bf16* src = fbf + (pbase + (long)t * 64 + ci) * 64 + ch * 16;
            uint4 v0 = *(const uint4*)src;
            uint4 v1 = *(const uint4*)(src + 8);
            *(uint4*)&Bb[ci * APAD + ch * 16] = v0;
            *(uint4*)&Bb[ci * APAD + ch * 16 + 8] = v1;
            if (tid < 64) SqC[tid] = sq[pbase + t * 64 + tid];
        }
        __syncthreads();   // B/SqC ready; prev selection (reads Dt) also done

        // MFMA phase: wave wv computes rows [wv*16, wv*16+16) x all 64 cands,
        // packs keys straight into Dt.
#pragma unroll
        for (int ct = 0; ct < 4; ++ct) {
            const __bf16* bp = &Bb[(ct * 16 + n16) * APAD + quad * 8];
            bf16x8 bf0 = *(const bf16x8*)bp;
            bf16x8 bf1 = *(const bf16x8*)(bp + 32);
            f32x4 acc = {0.f, 0.f, 0.f, 0.f};
            acc = __builtin_amdgcn_mfma_f32_16x16x32_bf16(af0, bf0, acc, 0, 0, 0);
            acc = __builtin_amdgcn_mfma_f32_16x16x32_bf16(af1, bf1, acc, 0, 0, 0);
            const int ccol = ct * 16 + n16;
            const float sqc = SqC[ccol];
            const unsigned int m = (unsigned int)(t * 64 + ccol);
#pragma unroll
            for (int rr = 0; rr < 4; ++rr) {
                const int rrow = wv * 16 + quad * 4 + rr;
                Dt[rrow * DPAD + ccol] = packkey(fmaf(-2.0f, acc[rr], sqc), m);
            }
        }
        __syncthreads();   // keys ready

        // selection: thread (r, slot) inserts its 16 keys, branchless
        const uint4* kp = (const uint4*)&Dt[r * DPAD + slot * 16];
#pragma unroll
        for (int q = 0; q < 4; ++q) {
            uint4 kv = kp[q];
            INSERT16(keys, kv.x);
            INSERT16(keys, kv.y);
            INSERT16(keys, kv.z);
            INSERT16(keys, kv.w);
        }
    }

    // merge: reuse Dt as staging; 4 sorted lists -> 32-cand union superset
    __syncthreads();
    {
        uint4* kw = (uint4*)&Dt[r * DPAD + slot * 16];
#pragma unroll
        for (int q = 0; q < 4; ++q)
            kw[q] = make_uint4(keys[4 * q], keys[4 * q + 1], keys[4 * q + 2], keys[4 * q + 3]);
    }
    __syncthreads();
    if (slot < 2) {
        const unsigned int* k0 = &Dt[r * DPAD + slot * 32];
        const unsigned int* k1 = k0 + 16;
        int mo[16];
#pragma unroll
        for (int j = 0; j < 16; ++j) {
            unsigned int a = k0[j], bv = k1[15 - j];
            mo[j] = (int)((a < bv ? a : bv) & 0x7FFu);
        }
        int4* op = (int4*)(idx32 + (pbase + row0 + r) * 32 + slot * 16);
#pragma unroll
        for (int q = 0; q < 4; ++q)
            op[q] = make_int4(mo[4 * q], mo[4 * q + 1], mo[4 * q + 2], mo[4 * q + 3]);
    }
}

// ---------------------------------------------------------------------------
// fp32 rescore of 32 filtered candidates -> exact top-16 (reference ranking
// and tie semantics via lexicographic (d2, idx) rank over the 32 candidates).
// Wave = 2 rows x 32 lanes; block = 8 rows.
// ---------------------------------------------------------------------------
template <int D>
__global__ __launch_bounds__(256) void knn_rescore_kernel(const float* __restrict__ feat,
                                                          const float* __restrict__ sq,
                                                          const int* __restrict__ idx32,
                                                          int* __restrict__ idx_out) {
    __shared__ float rowf[8][D];
    const int tid = threadIdx.x;
    const int w = tid >> 6, ln = tid & 63;
    const int rw = ln >> 5, c = ln & 31;
    const long pblk = (long)blockIdx.x * 8;
    const long p = pblk + w * 2 + rw;
    const long pbase = (p >> 11) << 11;

    for (int i = tid; i < 8 * D; i += 256) rowf[i / D][i % D] = feat[pblk * D + i];
    __syncthreads();

    const int j = idx32[p * 32 + c];
    const float* cp = feat + (pbase + j) * D;
    float dot;
    if constexpr (D == 64) {
        float a0 = 0.f, a1 = 0.f, a2 = 0.f, a3 = 0.f;
#pragma unroll
        for (int q = 0; q < 16; ++q) {
            float4 cv = ((const float4*)cp)[q];
            float4 rv = *(const float4*)&rowf[w * 2 + rw][q * 4];
            a0 = fmaf(rv.x, cv.x, a0);
            a1 = fmaf(rv.y, cv.y, a1);
            a2 = fmaf(rv.z, cv.z, a2);
            a3 = fmaf(rv.w, cv.w, a3);
        }
        dot = (a0 + a1) + (a2 + a3);
    } else {
        dot = fmaf(rowf[w * 2 + rw][0], cp[0],
              fmaf(rowf[w * 2 + rw][1], cp[1], rowf[w * 2 + rw][2] * cp[2]));
    }
    float score = fmaf(-2.0f, dot, sq[pbase + j]);

    int rank = 0;
    const int hb = ln & 32;
#pragma unroll
    for (int m = 0; m < 32; ++m) {
        float dm = __shfl(score, hb + m);
        int jm = __shfl(j, hb + m);
        rank += (dm < score || (dm == score && jm < j)) ? 1 : 0;
    }
    if (rank < KK) idx_out[p * KK + rank] = j;
}

// ---------------------------------------------------------------------------
// P[p][h] = b1[h] + sum_d f[p][d] * (w1[d][h] - w1[D+d][h])
// Q[p][h] =         sum_d f[p][d] *  w1[D+d][h]
// ---------------------------------------------------------------------------
template <int D>
__global__ __launch_bounds__(256) void pq_kernel(const float* __restrict__ feat,
                                                 const float* __restrict__ w1,
                                                 const float* __restrict__ b1,
                                                 float* __restrict__ P,
                                                 float* __restrict__ Q) {
    const int tid = threadIdx.x;
    const int h = tid & 63;
    const int pl = tid >> 6;
    const long p = (long)blockIdx.x * 4 + pl;   // p < BN
    const float* fp = feat + p * D;
    float accp = 0.f, accq = 0.f;
#pragma unroll
    for (int d = 0; d < D; ++d) {
        float fv = fp[d];
        float wa = w1[d * HH + h];
        float wb = w1[(D + d) * HH + h];
        accp = fmaf(fv, wa - wb, accp);
        accq = fmaf(fv, wb, accq);
    }
    P[p * HH + h] = accp + b1[h];
    Q[p * HH + h] = accq;
}

// ---------------------------------------------------------------------------
// R[p] = (1/K) sum_k relu(P[p] + Q[j_k]);  out[p] = R[p] @ wo + bo
// ---------------------------------------------------------------------------
__global__ __launch_bounds__(256) void gather_mlp_kernel(const float* __restrict__ P,
                                                         const float* __restrict__ Q,
                                                         const int* __restrict__ idx,
                                                         const float* __restrict__ wo,
                                                         const float* __restrict__ bo,
                                                         float* __restrict__ out) {
    __shared__ float Rl[4][HH];
    const int tid = threadIdx.x;
    const int h = tid & 63;
    const int pl = tid >> 6;
    const long p = (long)blockIdx.x * 4 + pl;
    const long bbase = (p >> 11) << 11;    // batch base point index
    const float Pv = P[p * HH + h];
    const int* ip = idx + p * KK;
    float acc = 0.f;
#pragma unroll
    for (int k = 0; k < KK; ++k) {
        int j = ip[k];
        float qv = Q[(bbase + j) * HH + h];
        acc += fmaxf(Pv + qv, 0.f);
    }
    acc *= (1.f / KK);
    Rl[pl][h] = acc;
    __syncthreads();
    float o = bo[h];
#pragma unroll
    for (int l = 0; l < HH; ++l) o = fmaf(Rl[pl][l], wo[l * HH + h], o);
    out[p * HH + h] = o;
}

// ---------------------------------------------------------------------------
// g[b] = mean_n feat[b,n,:];  out[b] = relu(g@fw1+fb1)@fw2+fb2
// ---------------------------------------------------------------------------
__global__ __launch_bounds__(256) void pool_head_kernel(const float* __restrict__ feat,
                                                        const float* __restrict__ fw1,
                                                        const float* __restrict__ fb1,
                                                        const float* __restrict__ fw2,
                                                        const float* __restrict__ fb2,
                                                        float* __restrict__ out) {
    __shared__ float part[4][HH];
    __shared__ float g[HH];
    __shared__ float tl[HH];
    const int b = blockIdx.x;
    const int tid = threadIdx.x;
    const int h = tid & 63;
    const int ch = tid >> 6;
    float s = 0.f;
    const float* fp = feat + ((long)b * NN + ch * 512) * HH + h;
    for (int n = 0; n < 512; ++n) s += fp[(long)n * HH];
    part[ch][h] = s;
    __syncthreads();
    if (tid < HH) g[h] = (part[0][h] + part[1][h] + part[2][h] + part[3][h]) * (1.f / NN);
    __syncthreads();
    if (tid < HH) {
        float a = fb1[h];
#pragma unroll
        for (int l = 0; l < HH; ++l) a = fmaf(g[l], fw1[l * HH + h], a);
        tl[h] = fmaxf(a, 0.f);
    }
    __syncthreads();
    if (tid < OUTC) {
        float o = fb2[tid];
#pragma unroll
        for (int l = 0; l < HH; ++l) o = fmaf(tl[l], fw2[l * OUTC + tid], o);
        out[(long)b * OUTC + tid] = o;
    }
}

// ---------------------------------------------------------------------------
extern "C" void kernel_launch(void* const* d_in, const int* in_sizes, int n_in,
                              void* d_out, int out_size, void* d_ws, size_t ws_size,
                              hipStream_t stream) {
    const float* x    = (const float*)d_in[0];
    const float* w1_0 = (const float*)d_in[1];
    const float* b1_0 = (const float*)d_in[2];
    const float* wo_0 = (const float*)d_in[3];
    const float* bo_0 = (const float*)d_in[4];
    const float* w1_1 = (const float*)d_in[5];
    const float* b1_1 = (const float*)d_in[6];
    const float* wo_1 = (const float*)d_in[7];
    const float* bo_1 = (const float*)d_in[8];
    const float* w1_2 = (const float*)d_in[9];
    const float* b1_2 = (const float*)d_in[10];
    const float* wo_2 = (const float*)d_in[11];
    const float* bo_2 = (const float*)d_in[12];
    const float* fw1  = (const float*)d_in[13];
    const float* fb1  = (const float*)d_in[14];
    const float* fw2  = (const float*)d_in[15];
    const float* fb2  = (const float*)d_in[16];
    float* out = (float*)d_out;

    // workspace layout (floats)
    float* featA = (float*)d_ws;
    float* featB = featA + (long)BN * HH;
    float* Pb    = featB + (long)BN * HH;
    float* Qb    = Pb + (long)BN * HH;
    float* sqb   = Qb + (long)BN * HH;
    int*   idxb  = (int*)(sqb + BN);

    // regions reused before pq_kernel writes Pb/Qb:
    int*    idx32 = (int*)Pb;           // filter output (BN x 32)
    __bf16* fbf   = (__bf16*)Qb;        // bf16 features (BN x 64)

    // ---- layer 0 (D=3) ----
    sq_kernel<3><<<BN / 256, 256, 0, stream>>>(x, sqb);
    knn3_filter_kernel<<<BB * 32, 256, 0, stream>>>(x, sqb, idx32);
    knn_rescore_kernel<3><<<BN / 8, 256, 0, stream>>>(x, sqb, idx32, idxb);
    pq_kernel<3><<<BN / 4, 256, 0, stream>>>(x, w1_0, b1_0, Pb, Qb);
    gather_mlp_kernel<<<BN / 4, 256, 0, stream>>>(Pb, Qb, idxb, wo_0, bo_0, featA);

    // ---- layer 1 (D=64) ----
    sq_kernel<64><<<BN / 256, 256, 0, stream>>>(featA, sqb);
    tobf16_kernel<<<BN * HH / 2048, 256, 0, stream>>>(featA, fbf);
    knn_filter_kernel<<<BB * 32, 256, 0, stream>>>(fbf, sqb, idx32);
    knn_rescore_kernel<64><<<BN / 8, 256, 0, stream>>>(featA, sqb, idx32, idxb);
    pq_kernel<64><<<BN / 4, 256, 0, stream>>>(featA, w1_1, b1_1, Pb, Qb);
    gather_mlp_kernel<<<BN / 4, 256, 0, stream>>>(Pb, Qb, idxb, wo_1, bo_1, featB);

    // ---- layer 2 (D=64) ----
    sq_kernel<64><<<BN / 256, 256, 0, stream>>>(featB, sqb);
    tobf16_kernel<<<BN * HH / 2048, 256, 0, stream>>>(featB, fbf);
    knn_filter_kernel<<<BB * 32, 256, 0, stream>>>(fbf, sqb, idx32);
    knn_rescore_kernel<64><<<BN / 8, 256, 0, stream>>>(featB, sqb, idx32, idxb);
    pq_kernel<64><<<BN / 4, 256, 0, stream>>>(featB, w1_2, b1_2, Pb, Qb);
    gather_mlp_kernel<<<BN / 4, 256, 0, stream>>>(Pb, Qb, idxb, wo_2, bo_2, featA);

    // ---- pool + head ----
    pool_head_kernel<<<BB, 256, 0, stream>>>(featA, fw1, fb1, fw2, fb2, out);
}

// Round 6
// 900.331 us; speedup vs baseline: 15.9298x; 1.2104x over previous
//
#include <hip/hip_runtime.h>

// Problem constants
#define BB 32
#define NN 2048
#define FF 3
#define HH 64
#define OUTC 128
#define KK 16
#define BN (BB * NN)   // 65536 points

typedef __attribute__((ext_vector_type(8))) __bf16 bf16x8;
typedef __attribute__((ext_vector_type(4))) float f32x4;

// Pack d2 + candidate index into one sortable u32:
// high 21 bits = monotone(float d2) truncated, low 11 bits = idx (NN=2^11).
__device__ __forceinline__ unsigned int packkey(float d2, unsigned int m) {
    unsigned int bb = __builtin_bit_cast(unsigned int, d2);
    unsigned int msk = (unsigned int)((int)bb >> 31);
    unsigned int srt = bb ^ (msk | 0x80000000u);
    return (srt & 0xFFFFF800u) | m;
}

__device__ __forceinline__ void ce(unsigned int& a, unsigned int& b) {
    unsigned int lo = a < b ? a : b;
    unsigned int hi = a < b ? b : a;
    a = lo; b = hi;
}

// Sort 16 keys ascending — Batcher odd-even mergesort (63 CE, branchless).
__device__ __forceinline__ void sort16(unsigned int k[16]) {
#pragma unroll
    for (int p = 1; p < 16; p <<= 1)
#pragma unroll
        for (int q = p; q >= 1; q >>= 1)
#pragma unroll
            for (int j = q % p; j + q < 16; j += 2 * q)
#pragma unroll
                for (int i = 0; i < q; ++i) {
                    int x = i + j, y = i + j + q;
                    if (y < 16 && (x / (2 * p) == y / (2 * p))) ce(k[x], k[y]);
                }
}

// keys (sorted asc) <- lowest-16 of union(keys, nk), nk sorted asc.
// Half-cleaner + 16-elem bitonic merge (16 + 64 inst).
__device__ __forceinline__ void merge16(unsigned int keys[16], const unsigned int nk[16]) {
    unsigned int t[16];
#pragma unroll
    for (int i = 0; i < 16; ++i) {
        unsigned int b = nk[15 - i];
        t[i] = keys[i] < b ? keys[i] : b;
    }
#pragma unroll
    for (int d = 8; d >= 1; d >>= 1)
#pragma unroll
        for (int i = 0; i < 16; ++i)
            if ((i & d) == 0) ce(t[i], t[i ^ d]);
#pragma unroll
    for (int i = 0; i < 16; ++i) keys[i] = t[i];
}

// ---------------------------------------------------------------------------
// sq[p] = sum_d feat[p][d]^2   (layer 0 only, D=3)
// ---------------------------------------------------------------------------
template <int D>
__global__ __launch_bounds__(256) void sq_kernel(const float* __restrict__ f,
                                                 float* __restrict__ sqo) {
    long p = (long)blockIdx.x * 256 + threadIdx.x;   // p < BN
    const float* fp = f + p * D;
    float s = 0.f;
#pragma unroll
    for (int d = 0; d < D; ++d) s = fmaf(fp[d], fp[d], s);
    sqo[p] = s;
}

// ---------------------------------------------------------------------------
// Fused fp32->bf16 conversion + sq (row sum of squares). 8 elems/thread,
// 8 threads/row (HH=64); row-sum via 3 shfl_xor.
// ---------------------------------------------------------------------------
__global__ __launch_bounds__(256) void tobf16sq_kernel(const float* __restrict__ f,
                                                       __bf16* __restrict__ o,
                                                       float* __restrict__ sqo) {
    const int tid = threadIdx.x;
    long base = ((long)blockIdx.x * 256 + tid) * 8;
    const float4* fp = (const float4*)(f + base);
    float4 v0 = fp[0], v1 = fp[1];
    unsigned short us[8];
    us[0] = __builtin_bit_cast(unsigned short, (__bf16)v0.x);
    us[1] = __builtin_bit_cast(unsigned short, (__bf16)v0.y);
    us[2] = __builtin_bit_cast(unsigned short, (__bf16)v0.z);
    us[3] = __builtin_bit_cast(unsigned short, (__bf16)v0.w);
    us[4] = __builtin_bit_cast(unsigned short, (__bf16)v1.x);
    us[5] = __builtin_bit_cast(unsigned short, (__bf16)v1.y);
    us[6] = __builtin_bit_cast(unsigned short, (__bf16)v1.z);
    us[7] = __builtin_bit_cast(unsigned short, (__bf16)v1.w);
    *(uint4*)(o + base) = *(const uint4*)us;

    float s = v0.x * v0.x + v0.y * v0.y + v0.z * v0.z + v0.w * v0.w
            + v1.x * v1.x + v1.y * v1.y + v1.z * v1.z + v1.w * v1.w;
    s += __shfl_xor(s, 1);
    s += __shfl_xor(s, 2);
    s += __shfl_xor(s, 4);
    if ((tid & 7) == 0) sqo[base / HH] = s;
}

// ---------------------------------------------------------------------------
// Layer-0 kNN filter (D=3, fp32 scores): block = 64 rows x 2048 cands.
// Thread = (row, slot of 4); per-thread register top-16 via sort16+merge16.
// Pairwise bitonic merge 4x16 -> two half-union top-16 sets = 32 cands.
// ---------------------------------------------------------------------------
__global__ __launch_bounds__(256) void knn3_filter_kernel(const float* __restrict__ x,
                                                          const float* __restrict__ sq,
                                                          int* __restrict__ idx32) {
    __shared__ float4 lds_c[256];
    __shared__ unsigned int Km[64 * 68];
    const int tid = threadIdx.x;
    const int b = blockIdx.x >> 5;
    const int rg = blockIdx.x & 31;
    const long pbase = (long)b * NN;
    const int r = tid >> 2, slot = tid & 3;
    const int row = rg * 64 + r;

    const float* rp = x + (pbase + row) * 3;
    const float xr0 = rp[0], xr1 = rp[1], xr2 = rp[2];

    unsigned int keys[KK];
#pragma unroll
    for (int j = 0; j < KK; ++j) keys[j] = 0xFFFFFFFFu;

    for (int t = 0; t < NN / 256; ++t) {
        __syncthreads();
        {
            const int m = t * 256 + tid;
            const float* cp = x + (pbase + m) * 3;
            lds_c[tid] = make_float4(cp[0], cp[1], cp[2], sq[pbase + m]);
        }
        __syncthreads();
        const int cbase = slot * 64;
#pragma unroll
        for (int bb = 0; bb < 4; ++bb) {
            unsigned int nk[16];
#pragma unroll
            for (int cc = 0; cc < 16; ++cc) {
                float4 v = lds_c[cbase + bb * 16 + cc];
                float dot = fmaf(xr0, v.x, fmaf(xr1, v.y, xr2 * v.z));
                float d2 = fmaf(-2.0f, dot, v.w);   // sq_row dropped (rank-invariant)
                nk[cc] = packkey(d2, (unsigned int)(t * 256 + cbase + bb * 16 + cc));
            }
            sort16(nk);
            merge16(keys, nk);
        }
    }

    // merge: 4 sorted lists -> 2 x (lowest-16 of half-union) = 32 cands
    {
        uint4* kw = (uint4*)&Km[r * 68 + slot * 16];
#pragma unroll
        for (int q = 0; q < 4; ++q)
            kw[q] = make_uint4(keys[4 * q], keys[4 * q + 1], keys[4 * q + 2], keys[4 * q + 3]);
    }
    __syncthreads();
    if (slot < 2) {
        const unsigned int* k0 = &Km[r * 68 + slot * 32];
        const unsigned int* k1 = k0 + 16;
        int mo[16];
#pragma unroll
        for (int j = 0; j < 16; ++j) {
            unsigned int a = k0[j], bv = k1[15 - j];
            mo[j] = (int)((a < bv ? a : bv) & 0x7FFu);
        }
        int4* op = (int4*)(idx32 + (pbase + row) * 32 + slot * 16);
#pragma unroll
        for (int q = 0; q < 4; ++q)
            op[q] = make_int4(mo[4 * q], mo[4 * q + 1], mo[4 * q + 2], mo[4 * q + 3]);
    }
}

// ---------------------------------------------------------------------------
// bf16-MFMA filter (D=64): block = 64 rows x 2048 cands of one batch.
// MFMA phase packs keys into Dt; selection = register sort16+merge16.
// ---------------------------------------------------------------------------
#define APAD 80   // LDS row stride (bf16 elems)
#define DPAD 68   // key-tile stride (u32); keeps 16B alignment for b128 reads

__global__ __launch_bounds__(256) void knn_filter_kernel(const __bf16* __restrict__ fbf,
                                                         const float* __restrict__ sq,
                                                         int* __restrict__ idx32) {
    __shared__ __align__(16) __bf16 Ab[64 * APAD];
    __shared__ __align__(16) __bf16 Bb[64 * APAD];
    __shared__ __align__(16) unsigned int Dt[64 * DPAD];
    __shared__ float SqC[64];

    const int tid = threadIdx.x;
    const int b = blockIdx.x >> 5;
    const int rg = blockIdx.x & 31;
    const long pbase = (long)b * NN;
    const int row0 = rg * 64;

    // stage A (64 rows x 64 dims bf16)
    {
        const int ri = tid >> 2, ch = tid & 3;
        const __bf16* src = fbf + (pbase + row0 + ri) * 64 + ch * 16;
        uint4 v0 = *(const uint4*)src;
        uint4 v1 = *(const uint4*)(src + 8);
        *(uint4*)&Ab[ri * APAD + ch * 16] = v0;
        *(uint4*)&Ab[ri * APAD + ch * 16 + 8] = v1;
    }
    __syncthreads();

    const int wv = tid >> 6, ln = tid & 63;
    const int n16 = ln & 15, quad = ln >> 4;
    bf16x8 af0, af1;
    {
        const __bf16* ap = &Ab[(wv * 16 + n16) * APAD + quad * 8];
        af0 = *(const bf16x8*)ap;
        af1 = *(const bf16x8*)(ap + 32);
    }

    const int r = tid >> 2, slot = tid & 3;
    unsigned int keys[KK];
#pragma unroll
    for (int j = 0; j < KK; ++j) keys[j] = 0xFFFFFFFFu;

    for (int t = 0; t < NN / 64; ++t) {
        // stage B tile (64 cands x 64 dims) + sq_c
        {
            const int ci = tid >> 2, ch = tid & 3;
            const __bf16* src = fbf + (pbase + (long)t * 64 + ci) * 64 + ch * 16;
            uint4 v0 = *(const uint4*)src;
            uint4 v1 = *(const uint4*)(src + 8);
            *(uint4*)&Bb[ci * APAD + ch * 16] = v0;
            *(uint4*)&Bb[ci * APAD + ch * 16 + 8] = v1;
            if (tid < 64) SqC[tid] = sq[pbase + t * 64 + tid];
        }
        __syncthreads();   // B/SqC ready; prev selection (reads Dt) also done

        // MFMA phase: wave wv computes rows [wv*16, wv*16+16) x all 64 cands,
        // packs keys straight into Dt.
#pragma unroll
        for (int ct = 0; ct < 4; ++ct) {
            const __bf16* bp = &Bb[(ct * 16 + n16) * APAD + quad * 8];
            bf16x8 bf0 = *(const bf16x8*)bp;
            bf16x8 bf1 = *(const bf16x8*)(bp + 32);
            f32x4 acc = {0.f, 0.f, 0.f, 0.f};
            acc = __builtin_amdgcn_mfma_f32_16x16x32_bf16(af0, bf0, acc, 0, 0, 0);
            acc = __builtin_amdgcn_mfma_f32_16x16x32_bf16(af1, bf1, acc, 0, 0, 0);
            const int ccol = ct * 16 + n16;
            const float sqc = SqC[ccol];
            const unsigned int m = (unsigned int)(t * 64 + ccol);
#pragma unroll
            for (int rr = 0; rr < 4; ++rr) {
                const int rrow = wv * 16 + quad * 4 + rr;
                Dt[rrow * DPAD + ccol] = packkey(fmaf(-2.0f, acc[rr], sqc), m);
            }
        }
        __syncthreads();   // keys ready

        // selection: thread (r, slot) sorts its 16 keys, merges into top-16
        {
            const uint4* kp = (const uint4*)&Dt[r * DPAD + slot * 16];
            unsigned int nk[16];
#pragma unroll
            for (int q = 0; q < 4; ++q) {
                uint4 kv = kp[q];
                nk[4 * q + 0] = kv.x; nk[4 * q + 1] = kv.y;
                nk[4 * q + 2] = kv.z; nk[4 * q + 3] = kv.w;
            }
            sort16(nk);
            merge16(keys, nk);
        }
    }

    // merge: reuse Dt as staging; 4 sorted lists -> 32-cand union superset
    __syncthreads();
    {
        uint4* kw = (uint4*)&Dt[r * DPAD + slot * 16];
#pragma unroll
        for (int q = 0; q < 4; ++q)
            kw[q] = make_uint4(keys[4 * q], keys[4 * q + 1], keys[4 * q + 2], keys[4 * q + 3]);
    }
    __syncthreads();
    if (slot < 2) {
        const unsigned int* k0 = &Dt[r * DPAD + slot * 32];
        const unsigned int* k1 = k0 + 16;
        int mo[16];
#pragma unroll
        for (int j = 0; j < 16; ++j) {
            unsigned int a = k0[j], bv = k1[15 - j];
            mo[j] = (int)((a < bv ? a : bv) & 0x7FFu);
        }
        int4* op = (int4*)(idx32 + (pbase + row0 + r) * 32 + slot * 16);
#pragma unroll
        for (int q = 0; q < 4; ++q)
            op[q] = make_int4(mo[4 * q], mo[4 * q + 1], mo[4 * q + 2], mo[4 * q + 3]);
    }
}

// ---------------------------------------------------------------------------
// fp32 rescore of 32 filtered candidates -> exact top-16 (reference ranking
// and tie semantics via lexicographic (d2, idx) rank over the 32 candidates).
// Wave = 2 rows x 32 lanes; block = 8 rows.
// ---------------------------------------------------------------------------
template <int D>
__global__ __launch_bounds__(256) void knn_rescore_kernel(const float* __restrict__ feat,
                                                          const float* __restrict__ sq,
                                                          const int* __restrict__ idx32,
                                                          int* __restrict__ idx_out) {
    __shared__ float rowf[8][D];
    const int tid = threadIdx.x;
    const int w = tid >> 6, ln = tid & 63;
    const int rw = ln >> 5, c = ln & 31;
    const long pblk = (long)blockIdx.x * 8;
    const long p = pblk + w * 2 + rw;
    const long pbase = (p >> 11) << 11;

    for (int i = tid; i < 8 * D; i += 256) rowf[i / D][i % D] = feat[pblk * D + i];
    __syncthreads();

    const int j = idx32[p * 32 + c];
    const float* cp = feat + (pbase + j) * D;
    float dot;
    if constexpr (D == 64) {
        float a0 = 0.f, a1 = 0.f, a2 = 0.f, a3 = 0.f;
#pragma unroll
        for (int q = 0; q < 16; ++q) {
            float4 cv = ((const float4*)cp)[q];
            float4 rv = *(const float4*)&rowf[w * 2 + rw][q * 4];
            a0 = fmaf(rv.x, cv.x, a0);
            a1 = fmaf(rv.y, cv.y, a1);
            a2 = fmaf(rv.z, cv.z, a2);
            a3 = fmaf(rv.w, cv.w, a3);
        }
        dot = (a0 + a1) + (a2 + a3);
    } else {
        dot = fmaf(rowf[w * 2 + rw][0], cp[0],
              fmaf(rowf[w * 2 + rw][1], cp[1], rowf[w * 2 + rw][2] * cp[2]));
    }
    float score = fmaf(-2.0f, dot, sq[pbase + j]);

    int rank = 0;
    const int hb = ln & 32;
#pragma unroll
    for (int m = 0; m < 32; ++m) {
        float dm = __shfl(score, hb + m);
        int jm = __shfl(j, hb + m);
        rank += (dm < score || (dm == score && jm < j)) ? 1 : 0;
    }
    if (rank < KK) idx_out[p * KK + rank] = j;
}

// ---------------------------------------------------------------------------
// P[p][h] = b1[h] + sum_d f[p][d] * (w1[d][h] - w1[D+d][h])
// Q[p][h] =         sum_d f[p][d] *  w1[D+d][h]
// ---------------------------------------------------------------------------
template <int D>
__global__ __launch_bounds__(256) void pq_kernel(const float* __restrict__ feat,
                                                 const float* __restrict__ w1,
                                                 const float* __restrict__ b1,
                                                 float* __restrict__ P,
                                                 float* __restrict__ Q) {
    const int tid = threadIdx.x;
    const int h = tid & 63;
    const int pl = tid >> 6;
    const long p = (long)blockIdx.x * 4 + pl;   // p < BN
    const float* fp = feat + p * D;
    float accp = 0.f, accq = 0.f;
#pragma unroll
    for (int d = 0; d < D; ++d) {
        float fv = fp[d];
        float wa = w1[d * HH + h];
        float wb = w1[(D + d) * HH + h];
        accp = fmaf(fv, wa - wb, accp);
        accq = fmaf(fv, wb, accq);
    }
    P[p * HH + h] = accp + b1[h];
    Q[p * HH + h] = accq;
}

// ---------------------------------------------------------------------------
// R[p] = (1/K) sum_k relu(P[p] + Q[j_k]);  out[p] = R[p] @ wo + bo
// ---------------------------------------------------------------------------
__global__ __launch_bounds__(256) void gather_mlp_kernel(const float* __restrict__ P,
                                                         const float* __restrict__ Q,
                                                         const int* __restrict__ idx,
                                                         const float* __restrict__ wo,
                                                         const float* __restrict__ bo,
                                                         float* __restrict__ out) {
    __shared__ float Rl[4][HH];
    const int tid = threadIdx.x;
    const int h = tid & 63;
    const int pl = tid >> 6;
    const long p = (long)blockIdx.x * 4 + pl;
    const long bbase = (p >> 11) << 11;    // batch base point index
    const float Pv = P[p * HH + h];
    const int* ip = idx + p * KK;
    float acc = 0.f;
#pragma unroll
    for (int k = 0; k < KK; ++k) {
        int j = ip[k];
        float qv = Q[(bbase + j) * HH + h];
        acc += fmaxf(Pv + qv, 0.f);
    }
    acc *= (1.f / KK);
    Rl[pl][h] = acc;
    __syncthreads();
    float o = bo[h];
#pragma unroll
    for (int l = 0; l < HH; ++l) o = fmaf(Rl[pl][l], wo[l * HH + h], o);
    out[p * HH + h] = o;
}

// ---------------------------------------------------------------------------
// g[b] = mean_n feat[b,n,:];  out[b] = relu(g@fw1+fb1)@fw2+fb2
// ---------------------------------------------------------------------------
__global__ __launch_bounds__(256) void pool_head_kernel(const float* __restrict__ feat,
                                                        const float* __restrict__ fw1,
                                                        const float* __restrict__ fb1,
                                                        const float* __restrict__ fw2,
                                                        const float* __restrict__ fb2,
                                                        float* __restrict__ out) {
    __shared__ float part[4][HH];
    __shared__ float g[HH];
    __shared__ float tl[HH];
    const int b = blockIdx.x;
    const int tid = threadIdx.x;
    const int h = tid & 63;
    const int ch = tid >> 6;
    float s = 0.f;
    const float* fp = feat + ((long)b * NN + ch * 512) * HH + h;
    for (int n = 0; n < 512; ++n) s += fp[(long)n * HH];
    part[ch][h] = s;
    __syncthreads();
    if (tid < HH) g[h] = (part[0][h] + part[1][h] + part[2][h] + part[3][h]) * (1.f / NN);
    __syncthreads();
    if (tid < HH) {
        float a = fb1[h];
#pragma unroll
        for (int l = 0; l < HH; ++l) a = fmaf(g[l], fw1[l * HH + h], a);
        tl[h] = fmaxf(a, 0.f);
    }
    __syncthreads();
    if (tid < OUTC) {
        float o = fb2[tid];
#pragma unroll
        for (int l = 0; l < HH; ++l) o = fmaf(tl[l], fw2[l * OUTC + tid], o);
        out[(long)b * OUTC + tid] = o;
    }
}

// ---------------------------------------------------------------------------
extern "C" void kernel_launch(void* const* d_in, const int* in_sizes, int n_in,
                              void* d_out, int out_size, void* d_ws, size_t ws_size,
                              hipStream_t stream) {
    const float* x    = (const float*)d_in[0];
    const float* w1_0 = (const float*)d_in[1];
    const float* b1_0 = (const float*)d_in[2];
    const float* wo_0 = (const float*)d_in[3];
    const float* bo_0 = (const float*)d_in[4];
    const float* w1_1 = (const float*)d_in[5];
    const float* b1_1 = (const float*)d_in[6];
    const float* wo_1 = (const float*)d_in[7];
    const float* bo_1 = (const float*)d_in[8];
    const float* w1_2 = (const float*)d_in[9];
    const float* b1_2 = (const float*)d_in[10];
    const float* wo_2 = (const float*)d_in[11];
    const float* bo_2 = (const float*)d_in[12];
    const float* fw1  = (const float*)d_in[13];
    const float* fb1  = (const float*)d_in[14];
    const float* fw2  = (const float*)d_in[15];
    const float* fb2  = (const float*)d_in[16];
    float* out = (float*)d_out;

    // workspace layout (floats)
    float* featA = (float*)d_ws;
    float* featB = featA + (long)BN * HH;
    float* Pb    = featB + (long)BN * HH;
    float* Qb    = Pb + (long)BN * HH;
    float* sqb   = Qb + (long)BN * HH;
    int*   idxb  = (int*)(sqb + BN);

    // regions reused before pq_kernel writes Pb/Qb:
    int*    idx32 = (int*)Pb;           // filter output (BN x 32)
    __bf16* fbf   = (__bf16*)Qb;        // bf16 features (BN x 64)

    // ---- layer 0 (D=3) ----
    sq_kernel<3><<<BN / 256, 256, 0, stream>>>(x, sqb);
    knn3_filter_kernel<<<BB * 32, 256, 0, stream>>>(x, sqb, idx32);
    knn_rescore_kernel<3><<<BN / 8, 256, 0, stream>>>(x, sqb, idx32, idxb);
    pq_kernel<3><<<BN / 4, 256, 0, stream>>>(x, w1_0, b1_0, Pb, Qb);
    gather_mlp_kernel<<<BN / 4, 256, 0, stream>>>(Pb, Qb, idxb, wo_0, bo_0, featA);

    // ---- layer 1 (D=64) ----
    tobf16sq_kernel<<<BN * HH / 2048, 256, 0, stream>>>(featA, fbf, sqb);
    knn_filter_kernel<<<BB * 32, 256, 0, stream>>>(fbf, sqb, idx32);
    knn_rescore_kernel<64><<<BN / 8, 256, 0, stream>>>(featA, sqb, idx32, idxb);
    pq_kernel<64><<<BN / 4, 256, 0, stream>>>(featA, w1_1, b1_1, Pb, Qb);
    gather_mlp_kernel<<<BN / 4, 256, 0, stream>>>(Pb, Qb, idxb, wo_1, bo_1, featB);

    // ---- layer 2 (D=64) ----
    tobf16sq_kernel<<<BN * HH / 2048, 256, 0, stream>>>(featB, fbf, sqb);
    knn_filter_kernel<<<BB * 32, 256, 0, stream>>>(fbf, sqb, idx32);
    knn_rescore_kernel<64><<<BN / 8, 256, 0, stream>>>(featB, sqb, idx32, idxb);
    pq_kernel<64><<<BN / 4, 256, 0, stream>>>(featB, w1_2, b1_2, Pb, Qb);
    gather_mlp_kernel<<<BN / 4, 256, 0, stream>>>(Pb, Qb, idxb, wo_2, bo_2, featA);

    // ---- pool + head ----
    pool_head_kernel<<<BB, 256, 0, stream>>>(featA, fw1, fb1, fw2, fb2, out);
}

// Round 7
// 856.992 us; speedup vs baseline: 16.7354x; 1.0506x over previous
//
#include <hip/hip_runtime.h>

// Problem constants
#define BB 32
#define NN 2048
#define FF 3
#define HH 64
#define OUTC 128
#define KK 16
#define BN (BB * NN)   // 65536 points

typedef __attribute__((ext_vector_type(8))) __bf16 bf16x8;
typedef __attribute__((ext_vector_type(4))) float f32x4;

// Pack d2 + candidate index into one sortable u32:
// high 21 bits = monotone(float d2) truncated, low 11 bits = idx (NN=2^11).
__device__ __forceinline__ unsigned int packkey(float d2, unsigned int m) {
    unsigned int bb = __builtin_bit_cast(unsigned int, d2);
    unsigned int msk = (unsigned int)((int)bb >> 31);
    unsigned int srt = bb ^ (msk | 0x80000000u);
    return (srt & 0xFFFFF800u) | m;
}

__device__ __forceinline__ void ce(unsigned int& a, unsigned int& b) {
    unsigned int lo = a < b ? a : b;
    unsigned int hi = a < b ? b : a;
    a = lo; b = hi;
}

// Sort 16 keys ascending — Batcher odd-even mergesort (63 CE, branchless).
__device__ __forceinline__ void sort16(unsigned int k[16]) {
#pragma unroll
    for (int p = 1; p < 16; p <<= 1)
#pragma unroll
        for (int q = p; q >= 1; q >>= 1)
#pragma unroll
            for (int j = q % p; j + q < 16; j += 2 * q)
#pragma unroll
                for (int i = 0; i < q; ++i) {
                    int x = i + j, y = i + j + q;
                    if (y < 16 && (x / (2 * p) == y / (2 * p))) ce(k[x], k[y]);
                }
}

// keys (sorted asc) <- lowest-16 of union(keys, nk), nk sorted asc.
__device__ __forceinline__ void merge16(unsigned int keys[16], const unsigned int nk[16]) {
    unsigned int t[16];
#pragma unroll
    for (int i = 0; i < 16; ++i) {
        unsigned int b = nk[15 - i];
        t[i] = keys[i] < b ? keys[i] : b;
    }
#pragma unroll
    for (int d = 8; d >= 1; d >>= 1)
#pragma unroll
        for (int i = 0; i < 16; ++i)
            if ((i & d) == 0) ce(t[i], t[i ^ d]);
#pragma unroll
    for (int i = 0; i < 16; ++i) keys[i] = t[i];
}

// ---------------------------------------------------------------------------
// prep3 (layer 0): sq + P/Q from x (D=3). Wave = one row (64 h-lanes).
// ---------------------------------------------------------------------------
__global__ __launch_bounds__(256) void prep3_kernel(const float* __restrict__ x,
                                                    const float* __restrict__ w1,
                                                    const float* __restrict__ b1,
                                                    float* __restrict__ sqo,
                                                    float* __restrict__ P,
                                                    float* __restrict__ Q) {
    const int tid = threadIdx.x;
    const int h = tid & 63;
    const int pl = tid >> 6;
    const long p = (long)blockIdx.x * 4 + pl;
    const float* fp = x + p * 3;
    const float f0 = fp[0], f1 = fp[1], f2 = fp[2];
    if (h == 0) sqo[p] = f0 * f0 + f1 * f1 + f2 * f2;
    float accp = 0.f, accq = 0.f;
    const float fv[3] = {f0, f1, f2};
#pragma unroll
    for (int d = 0; d < 3; ++d) {
        float wa = w1[d * HH + h];
        float wb = w1[(3 + d) * HH + h];
        accp = fmaf(fv[d], wa - wb, accp);
        accq = fmaf(fv[d], wb, accq);
    }
    P[p * HH + h] = accp + b1[h];
    Q[p * HH + h] = accq;
}

// ---------------------------------------------------------------------------
// prep64 (layers 1,2): fused bf16-convert + sq + P/Q. Wave = one row.
// ---------------------------------------------------------------------------
__global__ __launch_bounds__(256) void prep64_kernel(const float* __restrict__ feat,
                                                     const float* __restrict__ w1,
                                                     const float* __restrict__ b1,
                                                     __bf16* __restrict__ fbf,
                                                     float* __restrict__ sqo,
                                                     float* __restrict__ P,
                                                     float* __restrict__ Q) {
    const int tid = threadIdx.x;
    const int h = tid & 63;
    const int pl = tid >> 6;
    const long p = (long)blockIdx.x * 4 + pl;
    const float* fp = feat + p * HH;

    // lane-varying element: bf16 convert + squared-sum reduce
    float fvh = fp[h];
    fbf[p * HH + h] = (__bf16)fvh;
    float s = fvh * fvh;
    s += __shfl_xor(s, 1);
    s += __shfl_xor(s, 2);
    s += __shfl_xor(s, 4);
    s += __shfl_xor(s, 8);
    s += __shfl_xor(s, 16);
    s += __shfl_xor(s, 32);
    if (h == 0) sqo[p] = s;

    float accp = 0.f, accq = 0.f;
#pragma unroll
    for (int d = 0; d < HH; ++d) {
        float fv = fp[d];            // wave-uniform -> scalar load
        float wa = w1[d * HH + h];
        float wb = w1[(HH + d) * HH + h];
        accp = fmaf(fv, wa - wb, accp);
        accq = fmaf(fv, wb, accq);
    }
    P[p * HH + h] = accp + b1[h];
    Q[p * HH + h] = accq;
}

// ---------------------------------------------------------------------------
// Layer-0 kNN filter (D=3, fp32 scores, exact path preserved): block = 64
// rows x 2048 cands. Global loads for tile t+1 prefetched into registers
// during selection of tile t. Output: u16 candidate indices (BN x 32).
// ---------------------------------------------------------------------------
__global__ __launch_bounds__(256) void knn3_filter_kernel(const float* __restrict__ x,
                                                          const float* __restrict__ sq,
                                                          unsigned short* __restrict__ idx32) {
    __shared__ float4 lds_c[256];
    __shared__ unsigned int Km[64 * 68];
    const int tid = threadIdx.x;
    const int b = blockIdx.x >> 5;
    const int rg = blockIdx.x & 31;
    const long pbase = (long)b * NN;
    const int r = tid >> 2, slot = tid & 3;
    const int row = rg * 64 + r;

    const float* rp = x + (pbase + row) * 3;
    const float xr0 = rp[0], xr1 = rp[1], xr2 = rp[2];

    unsigned int keys[KK];
#pragma unroll
    for (int j = 0; j < KK; ++j) keys[j] = 0xFFFFFFFFu;

    // preload tile 0
    float c0, c1, c2, c3;
    {
        const float* cp = x + (pbase + tid) * 3;
        c0 = cp[0]; c1 = cp[1]; c2 = cp[2]; c3 = sq[pbase + tid];
    }

    for (int t = 0; t < NN / 256; ++t) {
        __syncthreads();                      // prev selection done reading lds_c
        lds_c[tid] = make_float4(c0, c1, c2, c3);
        __syncthreads();                      // tile ready
        if (t < NN / 256 - 1) {               // prefetch next tile (hidden by selection)
            const int m = (t + 1) * 256 + tid;
            const float* cp = x + (pbase + m) * 3;
            c0 = cp[0]; c1 = cp[1]; c2 = cp[2]; c3 = sq[pbase + m];
        }
        const int cbase = slot * 64;
#pragma unroll
        for (int bb = 0; bb < 4; ++bb) {
            unsigned int nk[16];
#pragma unroll
            for (int cc = 0; cc < 16; ++cc) {
                float4 v = lds_c[cbase + bb * 16 + cc];
                float dot = fmaf(xr0, v.x, fmaf(xr1, v.y, xr2 * v.z));
                float d2 = fmaf(-2.0f, dot, v.w);   // sq_row dropped (rank-invariant)
                nk[cc] = packkey(d2, (unsigned int)(t * 256 + cbase + bb * 16 + cc));
            }
            sort16(nk);
            merge16(keys, nk);
        }
    }

    // merge: 4 sorted lists -> 2 x (lowest-16 of half-union) = 32 cands
    {
        uint4* kw = (uint4*)&Km[r * 68 + slot * 16];
#pragma unroll
        for (int q = 0; q < 4; ++q)
            kw[q] = make_uint4(keys[4 * q], keys[4 * q + 1], keys[4 * q + 2], keys[4 * q + 3]);
    }
    __syncthreads();
    if (slot < 2) {
        const unsigned int* k0 = &Km[r * 68 + slot * 32];
        const unsigned int* k1 = k0 + 16;
        unsigned short ms[16];
#pragma unroll
        for (int j = 0; j < 16; ++j) {
            unsigned int a = k0[j], bv = k1[15 - j];
            ms[j] = (unsigned short)((a < bv ? a : bv) & 0x7FFu);
        }
        uint4* op = (uint4*)(idx32 + ((pbase + row) * 32 + slot * 16));
        op[0] = ((const uint4*)ms)[0];
        op[1] = ((const uint4*)ms)[1];
    }
}

// ---------------------------------------------------------------------------
// bf16-MFMA filter (D=64): block = 64 rows x 2048 cands. Register prefetch of
// next tile during selection; u16 output.
// ---------------------------------------------------------------------------
#define APAD 80   // LDS row stride (bf16 elems)
#define DPAD 68   // key-tile stride (u32)

__global__ __launch_bounds__(256) void knn_filter_kernel(const __bf16* __restrict__ fbf,
                                                         const float* __restrict__ sq,
                                                         unsigned short* __restrict__ idx32) {
    __shared__ __align__(16) __bf16 Ab[64 * APAD];
    __shared__ __align__(16) __bf16 Bb[64 * APAD];
    __shared__ __align__(16) unsigned int Dt[64 * DPAD];
    __shared__ float SqC[64];

    const int tid = threadIdx.x;
    const int b = blockIdx.x >> 5;
    const int rg = blockIdx.x & 31;
    const long pbase = (long)b * NN;
    const int row0 = rg * 64;
    const int ci = tid >> 2, ch = tid & 3;

    // stage A (64 rows x 64 dims bf16)
    {
        const __bf16* src = fbf + (pbase + row0 + ci) * 64 + ch * 16;
        uint4 v0 = *(const uint4*)src;
        uint4 v1 = *(const uint4*)(src + 8);
        *(uint4*)&Ab[ci * APAD + ch * 16] = v0;
        *(uint4*)&Ab[ci * APAD + ch * 16 + 8] = v1;
    }
    __syncthreads();

    const int wv = tid >> 6, ln = tid & 63;
    const int n16 = ln & 15, quad = ln >> 4;
    bf16x8 af0, af1;
    {
        const __bf16* ap = &Ab[(wv * 16 + n16) * APAD + quad * 8];
        af0 = *(const bf16x8*)ap;
        af1 = *(const bf16x8*)(ap + 32);
    }

    const int r = tid >> 2, slot = tid & 3;
    unsigned int keys[KK];
#pragma unroll
    for (int j = 0; j < KK; ++j) keys[j] = 0xFFFFFFFFu;

    // preload tile 0 into registers
    uint4 pv0, pv1;
    float psq;
    {
        const __bf16* src = fbf + (pbase + ci) * 64 + ch * 16;
        pv0 = *(const uint4*)src;
        pv1 = *(const uint4*)(src + 8);
        psq = (tid < 64) ? sq[pbase + tid] : 0.f;
    }

    for (int t = 0; t < NN / 64; ++t) {
        // write staged tile (registers -> LDS); safe: all Bb/SqC readers done
        *(uint4*)&Bb[ci * APAD + ch * 16] = pv0;
        *(uint4*)&Bb[ci * APAD + ch * 16 + 8] = pv1;
        if (tid < 64) SqC[tid] = psq;
        __syncthreads();   // barrier 1: Bb/SqC ready; prev selection done with Dt

        // MFMA phase: wave wv computes rows [wv*16, wv*16+16) x all 64 cands
#pragma unroll
        for (int ct = 0; ct < 4; ++ct) {
            const __bf16* bp = &Bb[(ct * 16 + n16) * APAD + quad * 8];
            bf16x8 bf0 = *(const bf16x8*)bp;
            bf16x8 bf1 = *(const bf16x8*)(bp + 32);
            f32x4 acc = {0.f, 0.f, 0.f, 0.f};
            acc = __builtin_amdgcn_mfma_f32_16x16x32_bf16(af0, bf0, acc, 0, 0, 0);
            acc = __builtin_amdgcn_mfma_f32_16x16x32_bf16(af1, bf1, acc, 0, 0, 0);
            const int ccol = ct * 16 + n16;
            const float sqc = SqC[ccol];
            const unsigned int m = (unsigned int)(t * 64 + ccol);
#pragma unroll
            for (int rr = 0; rr < 4; ++rr) {
                const int rrow = wv * 16 + quad * 4 + rr;
                Dt[rrow * DPAD + ccol] = packkey(fmaf(-2.0f, acc[rr], sqc), m);
            }
        }
        __syncthreads();   // barrier 2: Dt ready, Bb reads done

        // prefetch next tile into registers (latency hidden by selection)
        if (t < NN / 64 - 1) {
            const __bf16* src = fbf + (pbase + (long)(t + 1) * 64 + ci) * 64 + ch * 16;
            pv0 = *(const uint4*)src;
            pv1 = *(const uint4*)(src + 8);
            if (tid < 64) psq = sq[pbase + (t + 1) * 64 + tid];
        }

        // selection: thread (r, slot) sorts its 16 keys, merges into top-16
        {
            const uint4* kp = (const uint4*)&Dt[r * DPAD + slot * 16];
            unsigned int nk[16];
#pragma unroll
            for (int q = 0; q < 4; ++q) {
                uint4 kv = kp[q];
                nk[4 * q + 0] = kv.x; nk[4 * q + 1] = kv.y;
                nk[4 * q + 2] = kv.z; nk[4 * q + 3] = kv.w;
            }
            sort16(nk);
            merge16(keys, nk);
        }
    }

    // merge: reuse Dt as staging; 4 sorted lists -> 32-cand union superset
    __syncthreads();
    {
        uint4* kw = (uint4*)&Dt[r * DPAD + slot * 16];
#pragma unroll
        for (int q = 0; q < 4; ++q)
            kw[q] = make_uint4(keys[4 * q], keys[4 * q + 1], keys[4 * q + 2], keys[4 * q + 3]);
    }
    __syncthreads();
    if (slot < 2) {
        const unsigned int* k0 = &Dt[r * DPAD + slot * 32];
        const unsigned int* k1 = k0 + 16;
        unsigned short ms[16];
#pragma unroll
        for (int j = 0; j < 16; ++j) {
            unsigned int a = k0[j], bv = k1[15 - j];
            ms[j] = (unsigned short)((a < bv ? a : bv) & 0x7FFu);
        }
        uint4* op = (uint4*)(idx32 + ((pbase + row0 + r) * 32 + slot * 16));
        op[0] = ((const uint4*)ms)[0];
        op[1] = ((const uint4*)ms)[1];
    }
}

// ---------------------------------------------------------------------------
// Fused rescore + gather + edge-MLP. Block = 8 rows.
// Phase 1: exact fp32 rescore of 32 filtered cands -> top-16 (reference
//          ranking & tie semantics) kept in LDS.
// Phase 2: R = mean_k relu(P + Q[j_k]); out = R @ wo + bo.
// ---------------------------------------------------------------------------
template <int D>
__global__ __launch_bounds__(256) void rescore_gather_kernel(const float* __restrict__ feat,
                                                             const float* __restrict__ sq,
                                                             const unsigned short* __restrict__ idx32,
                                                             const float* __restrict__ P,
                                                             const float* __restrict__ Q,
                                                             const float* __restrict__ wo,
                                                             const float* __restrict__ bo,
                                                             float* __restrict__ outf) {
    __shared__ float rowf[8][D];
    __shared__ int Li[8][KK];
    __shared__ float Rl[8][HH];
    const int tid = threadIdx.x;
    const int w = tid >> 6, ln = tid & 63;
    const int rw = ln >> 5, c = ln & 31;
    const long pblk = (long)blockIdx.x * 8;
    const long p = pblk + w * 2 + rw;
    const long pbase = (p >> 11) << 11;

    for (int i = tid; i < 8 * D; i += 256) rowf[i / D][i % D] = feat[pblk * D + i];
    __syncthreads();

    const int j = (int)idx32[p * 32 + c];
    const float* cp = feat + (pbase + j) * D;
    float dot;
    if constexpr (D == 64) {
        float a0 = 0.f, a1 = 0.f, a2 = 0.f, a3 = 0.f;
#pragma unroll
        for (int q = 0; q < 16; ++q) {
            float4 cv = ((const float4*)cp)[q];
            float4 rv = *(const float4*)&rowf[w * 2 + rw][q * 4];
            a0 = fmaf(rv.x, cv.x, a0);
            a1 = fmaf(rv.y, cv.y, a1);
            a2 = fmaf(rv.z, cv.z, a2);
            a3 = fmaf(rv.w, cv.w, a3);
        }
        dot = (a0 + a1) + (a2 + a3);
    } else {
        dot = fmaf(rowf[w * 2 + rw][0], cp[0],
              fmaf(rowf[w * 2 + rw][1], cp[1], rowf[w * 2 + rw][2] * cp[2]));
    }
    float score = fmaf(-2.0f, dot, sq[pbase + j]);

    int rank = 0;
    const int hb = ln & 32;
#pragma unroll
    for (int m = 0; m < 32; ++m) {
        float dm = __shfl(score, hb + m);
        int jm = __shfl(j, hb + m);
        rank += (dm < score || (dm == score && jm < j)) ? 1 : 0;
    }
    if (rank < KK) Li[w * 2 + rw][rank] = j;
    __syncthreads();

    // Phase 2: gather + MLP for the 8 rows
    const int h = tid & 63, pl = tid >> 6;
#pragma unroll
    for (int rr0 = 0; rr0 < 2; ++rr0) {
        const int rr = pl + rr0 * 4;
        const long pp = pblk + rr;
        const long bb2 = (pp >> 11) << 11;
        const float Pv = P[pp * HH + h];
        float acc = 0.f;
#pragma unroll
        for (int k = 0; k < KK; ++k) {
            int j2 = Li[rr][k];
            acc += fmaxf(Pv + Q[(bb2 + j2) * HH + h], 0.f);
        }
        Rl[rr][h] = acc * (1.f / KK);
    }
    __syncthreads();
#pragma unroll
    for (int rr0 = 0; rr0 < 2; ++rr0) {
        const int rr = pl + rr0 * 4;
        float o = bo[h];
#pragma unroll
        for (int l = 0; l < HH; ++l) o = fmaf(Rl[rr][l], wo[l * HH + h], o);
        outf[(pblk + rr) * HH + h] = o;
    }
}

// ---------------------------------------------------------------------------
// g[b] = mean_n feat[b,n,:];  out[b] = relu(g@fw1+fb1)@fw2+fb2
// ---------------------------------------------------------------------------
__global__ __launch_bounds__(256) void pool_head_kernel(const float* __restrict__ feat,
                                                        const float* __restrict__ fw1,
                                                        const float* __restrict__ fb1,
                                                        const float* __restrict__ fw2,
                                                        const float* __restrict__ fb2,
                                                        float* __restrict__ out) {
    __shared__ float part[4][HH];
    __shared__ float g[HH];
    __shared__ float tl[HH];
    const int b = blockIdx.x;
    const int tid = threadIdx.x;
    const int h = tid & 63;
    const int ch = tid >> 6;
    float s = 0.f;
    const float* fp = feat + ((long)b * NN + ch * 512) * HH + h;
    for (int n = 0; n < 512; ++n) s += fp[(long)n * HH];
    part[ch][h] = s;
    __syncthreads();
    if (tid < HH) g[h] = (part[0][h] + part[1][h] + part[2][h] + part[3][h]) * (1.f / NN);
    __syncthreads();
    if (tid < HH) {
        float a = fb1[h];
#pragma unroll
        for (int l = 0; l < HH; ++l) a = fmaf(g[l], fw1[l * HH + h], a);
        tl[h] = fmaxf(a, 0.f);
    }
    __syncthreads();
    if (tid < OUTC) {
        float o = fb2[tid];
#pragma unroll
        for (int l = 0; l < HH; ++l) o = fmaf(tl[l], fw2[l * OUTC + tid], o);
        out[(long)b * OUTC + tid] = o;
    }
}

// ---------------------------------------------------------------------------
extern "C" void kernel_launch(void* const* d_in, const int* in_sizes, int n_in,
                              void* d_out, int out_size, void* d_ws, size_t ws_size,
                              hipStream_t stream) {
    const float* x    = (const float*)d_in[0];
    const float* w1_0 = (const float*)d_in[1];
    const float* b1_0 = (const float*)d_in[2];
    const float* wo_0 = (const float*)d_in[3];
    const float* bo_0 = (const float*)d_in[4];
    const float* w1_1 = (const float*)d_in[5];
    const float* b1_1 = (const float*)d_in[6];
    const float* wo_1 = (const float*)d_in[7];
    const float* bo_1 = (const float*)d_in[8];
    const float* w1_2 = (const float*)d_in[9];
    const float* b1_2 = (const float*)d_in[10];
    const float* wo_2 = (const float*)d_in[11];
    const float* bo_2 = (const float*)d_in[12];
    const float* fw1  = (const float*)d_in[13];
    const float* fb1  = (const float*)d_in[14];
    const float* fw2  = (const float*)d_in[15];
    const float* fb2  = (const float*)d_in[16];
    float* out = (float*)d_out;

    // workspace layout (floats)
    float* featA = (float*)d_ws;
    float* featB = featA + (long)BN * HH;
    float* Pb    = featB + (long)BN * HH;
    float* Qb    = Pb + (long)BN * HH;
    float* sqb   = Qb + (long)BN * HH;
    unsigned short* idx32 = (unsigned short*)(sqb + BN);   // BN x 32 u16 (4.2 MB)

    // bf16 feature mirrors alias the OPPOSITE feature buffer (consumed by the
    // filter before rescore_gather rewrites that buffer)
    __bf16* fbf1 = (__bf16*)featB;   // layer 1 (featB rewritten after filter)
    __bf16* fbf2 = (__bf16*)featA;   // layer 2 (featA rewritten after filter)

    // ---- layer 0 (D=3, exact fp32 kNN) ----
    prep3_kernel<<<BN / 4, 256, 0, stream>>>(x, w1_0, b1_0, sqb, Pb, Qb);
    knn3_filter_kernel<<<BB * 32, 256, 0, stream>>>(x, sqb, idx32);
    rescore_gather_kernel<3><<<BN / 8, 256, 0, stream>>>(x, sqb, idx32, Pb, Qb, wo_0, bo_0, featA);

    // ---- layer 1 (D=64) ----
    prep64_kernel<<<BN / 4, 256, 0, stream>>>(featA, w1_1, b1_1, fbf1, sqb, Pb, Qb);
    knn_filter_kernel<<<BB * 32, 256, 0, stream>>>(fbf1, sqb, idx32);
    rescore_gather_kernel<64><<<BN / 8, 256, 0, stream>>>(featA, sqb, idx32, Pb, Qb, wo_1, bo_1, featB);

    // ---- layer 2 (D=64) ----
    prep64_kernel<<<BN / 4, 256, 0, stream>>>(featB, w1_2, b1_2, fbf2, sqb, Pb, Qb);
    knn_filter_kernel<<<BB * 32, 256, 0, stream>>>(fbf2, sqb, idx32);
    rescore_gather_kernel<64><<<BN / 8, 256, 0, stream>>>(featB, sqb, idx32, Pb, Qb, wo_2, bo_2, featA);

    // ---- pool + head ----
    pool_head_kernel<<<BB, 256, 0, stream>>>(featA, fw1, fb1, fw2, fb2, out);
}

// Round 8
// 804.945 us; speedup vs baseline: 17.8175x; 1.0647x over previous
//
#include <hip/hip_runtime.h>

// Problem constants
#define BB 32
#define NN 2048
#define FF 3
#define HH 64
#define OUTC 128
#define KK 16
#define BN (BB * NN)   // 65536 points

typedef __attribute__((ext_vector_type(8))) __bf16 bf16x8;
typedef __attribute__((ext_vector_type(4))) float f32x4;

// Pack d2 + candidate index into one sortable u32:
// high 21 bits = monotone(float d2) truncated, low 11 bits = idx (NN=2^11).
__device__ __forceinline__ unsigned int packkey(float d2, unsigned int m) {
    unsigned int bb = __builtin_bit_cast(unsigned int, d2);
    unsigned int msk = (unsigned int)((int)bb >> 31);
    unsigned int srt = bb ^ (msk | 0x80000000u);
    return (srt & 0xFFFFF800u) | m;
}

__device__ __forceinline__ void ce(unsigned int& a, unsigned int& b) {
    unsigned int lo = a < b ? a : b;
    unsigned int hi = a < b ? b : a;
    a = lo; b = hi;
}

// Sort 16 keys ascending — Batcher odd-even mergesort (63 CE, branchless).
__device__ __forceinline__ void sort16(unsigned int k[16]) {
#pragma unroll
    for (int p = 1; p < 16; p <<= 1)
#pragma unroll
        for (int q = p; q >= 1; q >>= 1)
#pragma unroll
            for (int j = q % p; j + q < 16; j += 2 * q)
#pragma unroll
                for (int i = 0; i < q; ++i) {
                    int x = i + j, y = i + j + q;
                    if (y < 16 && (x / (2 * p) == y / (2 * p))) ce(k[x], k[y]);
                }
}

// keys (sorted asc) <- lowest-16 of union(keys, nk), nk sorted asc.
__device__ __forceinline__ void merge16(unsigned int keys[16], const unsigned int nk[16]) {
    unsigned int t[16];
#pragma unroll
    for (int i = 0; i < 16; ++i) {
        unsigned int b = nk[15 - i];
        t[i] = keys[i] < b ? keys[i] : b;
    }
#pragma unroll
    for (int d = 8; d >= 1; d >>= 1)
#pragma unroll
        for (int i = 0; i < 16; ++i)
            if ((i & d) == 0) ce(t[i], t[i ^ d]);
#pragma unroll
    for (int i = 0; i < 16; ++i) keys[i] = t[i];
}

// ---------------------------------------------------------------------------
// prep3 (layer 0): sq + P/Q from x (D=3). Wave = one row (64 h-lanes).
// ---------------------------------------------------------------------------
__global__ __launch_bounds__(256) void prep3_kernel(const float* __restrict__ x,
                                                    const float* __restrict__ w1,
                                                    const float* __restrict__ b1,
                                                    float* __restrict__ sqo,
                                                    float* __restrict__ P,
                                                    float* __restrict__ Q) {
    const int tid = threadIdx.x;
    const int h = tid & 63;
    const int pl = tid >> 6;
    const long p = (long)blockIdx.x * 4 + pl;
    const float* fp = x + p * 3;
    const float f0 = fp[0], f1 = fp[1], f2 = fp[2];
    if (h == 0) sqo[p] = f0 * f0 + f1 * f1 + f2 * f2;
    float accp = 0.f, accq = 0.f;
    const float fv[3] = {f0, f1, f2};
#pragma unroll
    for (int d = 0; d < 3; ++d) {
        float wa = w1[d * HH + h];
        float wb = w1[(3 + d) * HH + h];
        accp = fmaf(fv[d], wa - wb, accp);
        accq = fmaf(fv[d], wb, accq);
    }
    P[p * HH + h] = accp + b1[h];
    Q[p * HH + h] = accq;
}

// ---------------------------------------------------------------------------
// prep64 (layers 1,2): fused bf16-convert + sq + P/Q. Wave = one row.
// ---------------------------------------------------------------------------
__global__ __launch_bounds__(256) void prep64_kernel(const float* __restrict__ feat,
                                                     const float* __restrict__ w1,
                                                     const float* __restrict__ b1,
                                                     __bf16* __restrict__ fbf,
                                                     float* __restrict__ sqo,
                                                     float* __restrict__ P,
                                                     float* __restrict__ Q) {
    const int tid = threadIdx.x;
    const int h = tid & 63;
    const int pl = tid >> 6;
    const long p = (long)blockIdx.x * 4 + pl;
    const float* fp = feat + p * HH;

    // lane-varying element: bf16 convert + squared-sum reduce
    float fvh = fp[h];
    fbf[p * HH + h] = (__bf16)fvh;
    float s = fvh * fvh;
    s += __shfl_xor(s, 1);
    s += __shfl_xor(s, 2);
    s += __shfl_xor(s, 4);
    s += __shfl_xor(s, 8);
    s += __shfl_xor(s, 16);
    s += __shfl_xor(s, 32);
    if (h == 0) sqo[p] = s;

    float accp = 0.f, accq = 0.f;
#pragma unroll
    for (int d = 0; d < HH; ++d) {
        float fv = fp[d];            // wave-uniform -> scalar load
        float wa = w1[d * HH + h];
        float wb = w1[(HH + d) * HH + h];
        accp = fmaf(fv, wa - wb, accp);
        accq = fmaf(fv, wb, accq);
    }
    P[p * HH + h] = accp + b1[h];
    Q[p * HH + h] = accq;
}

// ---------------------------------------------------------------------------
// Layer-0 kNN filter (D=3, fp32 scores, exact path preserved): block = 64
// rows x 2048 cands. Register prefetch; XCD-pinned batches; u16 output.
// ---------------------------------------------------------------------------
__global__ __launch_bounds__(256) void knn3_filter_kernel(const float* __restrict__ x,
                                                          const float* __restrict__ sq,
                                                          unsigned short* __restrict__ idx32) {
    __shared__ float4 lds_c[256];
    __shared__ unsigned int Km[64 * 68];
    const int tid = threadIdx.x;
    // batch->XCD pinning: blocks with blockIdx%8==x land on XCD x (heuristic)
    const int xcd = blockIdx.x & 7;
    const int ii = blockIdx.x >> 3;          // 0..127
    const int b = xcd + 8 * (ii >> 5);       // 4 batches per XCD
    const int rg = ii & 31;
    const long pbase = (long)b * NN;
    const int r = tid >> 2, slot = tid & 3;
    const int row = rg * 64 + r;

    const float* rp = x + (pbase + row) * 3;
    const float xr0 = rp[0], xr1 = rp[1], xr2 = rp[2];

    unsigned int keys[KK];
#pragma unroll
    for (int j = 0; j < KK; ++j) keys[j] = 0xFFFFFFFFu;

    // preload tile 0
    float c0, c1, c2, c3;
    {
        const float* cp = x + (pbase + tid) * 3;
        c0 = cp[0]; c1 = cp[1]; c2 = cp[2]; c3 = sq[pbase + tid];
    }

    for (int t = 0; t < NN / 256; ++t) {
        __syncthreads();                      // prev selection done reading lds_c
        lds_c[tid] = make_float4(c0, c1, c2, c3);
        __syncthreads();                      // tile ready
        if (t < NN / 256 - 1) {               // prefetch next tile (hidden by selection)
            const int m = (t + 1) * 256 + tid;
            const float* cp = x + (pbase + m) * 3;
            c0 = cp[0]; c1 = cp[1]; c2 = cp[2]; c3 = sq[pbase + m];
        }
        const int cbase = slot * 64;
#pragma unroll
        for (int bb = 0; bb < 4; ++bb) {
            unsigned int nk[16];
#pragma unroll
            for (int cc = 0; cc < 16; ++cc) {
                float4 v = lds_c[cbase + bb * 16 + cc];
                float dot = fmaf(xr0, v.x, fmaf(xr1, v.y, xr2 * v.z));
                float d2 = fmaf(-2.0f, dot, v.w);   // sq_row dropped (rank-invariant)
                nk[cc] = packkey(d2, (unsigned int)(t * 256 + cbase + bb * 16 + cc));
            }
            sort16(nk);
            merge16(keys, nk);
        }
    }

    // merge: 4 sorted lists -> 2 x (lowest-16 of half-union) = 32 cands
    {
        uint4* kw = (uint4*)&Km[r * 68 + slot * 16];
#pragma unroll
        for (int q = 0; q < 4; ++q)
            kw[q] = make_uint4(keys[4 * q], keys[4 * q + 1], keys[4 * q + 2], keys[4 * q + 3]);
    }
    __syncthreads();
    if (slot < 2) {
        const unsigned int* k0 = &Km[r * 68 + slot * 32];
        const unsigned int* k1 = k0 + 16;
        unsigned short ms[16];
#pragma unroll
        for (int j = 0; j < 16; ++j) {
            unsigned int a = k0[j], bv = k1[15 - j];
            ms[j] = (unsigned short)((a < bv ? a : bv) & 0x7FFu);
        }
        uint4* op = (uint4*)(idx32 + ((pbase + row) * 32 + slot * 16));
        op[0] = ((const uint4*)ms)[0];
        op[1] = ((const uint4*)ms)[1];
    }
}

// ---------------------------------------------------------------------------
// bf16-MFMA filter (D=64): block = 64 rows x 2048 cands. Register prefetch,
// XCD-pinned batches, u16 output.
// ---------------------------------------------------------------------------
#define APAD 80   // LDS row stride (bf16 elems)
#define DPAD 68   // key-tile stride (u32)

__global__ __launch_bounds__(256) void knn_filter_kernel(const __bf16* __restrict__ fbf,
                                                         const float* __restrict__ sq,
                                                         unsigned short* __restrict__ idx32) {
    __shared__ __align__(16) __bf16 Ab[64 * APAD];
    __shared__ __align__(16) __bf16 Bb[64 * APAD];
    __shared__ __align__(16) unsigned int Dt[64 * DPAD];
    __shared__ float SqC[64];

    const int tid = threadIdx.x;
    const int xcd = blockIdx.x & 7;
    const int ii = blockIdx.x >> 3;          // 0..127
    const int b = xcd + 8 * (ii >> 5);       // 4 batches per XCD
    const int rg = ii & 31;
    const long pbase = (long)b * NN;
    const int row0 = rg * 64;
    const int ci = tid >> 2, ch = tid & 3;

    // stage A (64 rows x 64 dims bf16)
    {
        const __bf16* src = fbf + (pbase + row0 + ci) * 64 + ch * 16;
        uint4 v0 = *(const uint4*)src;
        uint4 v1 = *(const uint4*)(src + 8);
        *(uint4*)&Ab[ci * APAD + ch * 16] = v0;
        *(uint4*)&Ab[ci * APAD + ch * 16 + 8] = v1;
    }
    __syncthreads();

    const int wv = tid >> 6, ln = tid & 63;
    const int n16 = ln & 15, quad = ln >> 4;
    bf16x8 af0, af1;
    {
        const __bf16* ap = &Ab[(wv * 16 + n16) * APAD + quad * 8];
        af0 = *(const bf16x8*)ap;
        af1 = *(const bf16x8*)(ap + 32);
    }

    const int r = tid >> 2, slot = tid & 3;
    unsigned int keys[KK];
#pragma unroll
    for (int j = 0; j < KK; ++j) keys[j] = 0xFFFFFFFFu;

    // preload tile 0 into registers
    uint4 pv0, pv1;
    float psq;
    {
        const __bf16* src = fbf + (pbase + ci) * 64 + ch * 16;
        pv0 = *(const uint4*)src;
        pv1 = *(const uint4*)(src + 8);
        psq = (tid < 64) ? sq[pbase + tid] : 0.f;
    }

    for (int t = 0; t < NN / 64; ++t) {
        // write staged tile (registers -> LDS); safe: all Bb/SqC readers done
        *(uint4*)&Bb[ci * APAD + ch * 16] = pv0;
        *(uint4*)&Bb[ci * APAD + ch * 16 + 8] = pv1;
        if (tid < 64) SqC[tid] = psq;
        __syncthreads();   // barrier 1: Bb/SqC ready; prev selection done with Dt

        // MFMA phase: wave wv computes rows [wv*16, wv*16+16) x all 64 cands
#pragma unroll
        for (int ct = 0; ct < 4; ++ct) {
            const __bf16* bp = &Bb[(ct * 16 + n16) * APAD + quad * 8];
            bf16x8 bf0 = *(const bf16x8*)bp;
            bf16x8 bf1 = *(const bf16x8*)(bp + 32);
            f32x4 acc = {0.f, 0.f, 0.f, 0.f};
            acc = __builtin_amdgcn_mfma_f32_16x16x32_bf16(af0, bf0, acc, 0, 0, 0);
            acc = __builtin_amdgcn_mfma_f32_16x16x32_bf16(af1, bf1, acc, 0, 0, 0);
            const int ccol = ct * 16 + n16;
            const float sqc = SqC[ccol];
            const unsigned int m = (unsigned int)(t * 64 + ccol);
#pragma unroll
            for (int rr = 0; rr < 4; ++rr) {
                const int rrow = wv * 16 + quad * 4 + rr;
                Dt[rrow * DPAD + ccol] = packkey(fmaf(-2.0f, acc[rr], sqc), m);
            }
        }
        __syncthreads();   // barrier 2: Dt ready, Bb reads done

        // prefetch next tile into registers (latency hidden by selection)
        if (t < NN / 64 - 1) {
            const __bf16* src = fbf + (pbase + (long)(t + 1) * 64 + ci) * 64 + ch * 16;
            pv0 = *(const uint4*)src;
            pv1 = *(const uint4*)(src + 8);
            if (tid < 64) psq = sq[pbase + (t + 1) * 64 + tid];
        }

        // selection: thread (r, slot) sorts its 16 keys, merges into top-16
        {
            const uint4* kp = (const uint4*)&Dt[r * DPAD + slot * 16];
            unsigned int nk[16];
#pragma unroll
            for (int q = 0; q < 4; ++q) {
                uint4 kv = kp[q];
                nk[4 * q + 0] = kv.x; nk[4 * q + 1] = kv.y;
                nk[4 * q + 2] = kv.z; nk[4 * q + 3] = kv.w;
            }
            sort16(nk);
            merge16(keys, nk);
        }
    }

    // merge: reuse Dt as staging; 4 sorted lists -> 32-cand union superset
    __syncthreads();
    {
        uint4* kw = (uint4*)&Dt[r * DPAD + slot * 16];
#pragma unroll
        for (int q = 0; q < 4; ++q)
            kw[q] = make_uint4(keys[4 * q], keys[4 * q + 1], keys[4 * q + 2], keys[4 * q + 3]);
    }
    __syncthreads();
    if (slot < 2) {
        const unsigned int* k0 = &Dt[r * DPAD + slot * 32];
        const unsigned int* k1 = k0 + 16;
        unsigned short ms[16];
#pragma unroll
        for (int j = 0; j < 16; ++j) {
            unsigned int a = k0[j], bv = k1[15 - j];
            ms[j] = (unsigned short)((a < bv ? a : bv) & 0x7FFu);
        }
        uint4* op = (uint4*)(idx32 + ((pbase + row0 + r) * 32 + slot * 16));
        op[0] = ((const uint4*)ms)[0];
        op[1] = ((const uint4*)ms)[1];
    }
}

// ---------------------------------------------------------------------------
// Fused rescore + gather + edge-MLP, XCD-pinned batches. Block = 8 rows.
// ---------------------------------------------------------------------------
template <int D>
__global__ __launch_bounds__(256) void rescore_gather_kernel(const float* __restrict__ feat,
                                                             const float* __restrict__ sq,
                                                             const unsigned short* __restrict__ idx32,
                                                             const float* __restrict__ P,
                                                             const float* __restrict__ Q,
                                                             const float* __restrict__ wo,
                                                             const float* __restrict__ bo,
                                                             float* __restrict__ outf) {
    __shared__ float rowf[8][D];
    __shared__ int Li[8][KK];
    __shared__ float Rl[8][HH];
    const int tid = threadIdx.x;
    const int w = tid >> 6, ln = tid & 63;
    const int rw = ln >> 5, c = ln & 31;
    // batch->XCD pinning: each XCD's L2 sees only 4 batches' gather set
    const int xcd = blockIdx.x & 7;
    const int ii = blockIdx.x >> 3;            // 0..1023
    const int batch = xcd + 8 * (ii >> 8);     // 4 batches per XCD
    const int rb = ii & 255;
    const long pbase = (long)batch * NN;
    const long pblk = pbase + (long)rb * 8;
    const long p = pblk + w * 2 + rw;

    for (int i = tid; i < 8 * D; i += 256) rowf[i / D][i % D] = feat[pblk * D + i];
    __syncthreads();

    const int j = (int)idx32[p * 32 + c];
    const float* cp = feat + (pbase + j) * D;
    float dot;
    if constexpr (D == 64) {
        float a0 = 0.f, a1 = 0.f, a2 = 0.f, a3 = 0.f;
#pragma unroll
        for (int q = 0; q < 16; ++q) {
            float4 cv = ((const float4*)cp)[q];
            float4 rv = *(const float4*)&rowf[w * 2 + rw][q * 4];
            a0 = fmaf(rv.x, cv.x, a0);
            a1 = fmaf(rv.y, cv.y, a1);
            a2 = fmaf(rv.z, cv.z, a2);
            a3 = fmaf(rv.w, cv.w, a3);
        }
        dot = (a0 + a1) + (a2 + a3);
    } else {
        dot = fmaf(rowf[w * 2 + rw][0], cp[0],
              fmaf(rowf[w * 2 + rw][1], cp[1], rowf[w * 2 + rw][2] * cp[2]));
    }
    float score = fmaf(-2.0f, dot, sq[pbase + j]);

    int rank = 0;
    const int hb = ln & 32;
#pragma unroll
    for (int m = 0; m < 32; ++m) {
        float dm = __shfl(score, hb + m);
        int jm = __shfl(j, hb + m);
        rank += (dm < score || (dm == score && jm < j)) ? 1 : 0;
    }
    if (rank < KK) Li[w * 2 + rw][rank] = j;
    __syncthreads();

    // Phase 2: gather + MLP for the 8 rows
    const int h = tid & 63, pl = tid >> 6;
#pragma unroll
    for (int rr0 = 0; rr0 < 2; ++rr0) {
        const int rr = pl + rr0 * 4;
        const long pp = pblk + rr;
        const float Pv = P[pp * HH + h];
        float acc = 0.f;
#pragma unroll
        for (int k = 0; k < KK; ++k) {
            int j2 = Li[rr][k];
            acc += fmaxf(Pv + Q[(pbase + j2) * HH + h], 0.f);
        }
        Rl[rr][h] = acc * (1.f / KK);
    }
    __syncthreads();
#pragma unroll
    for (int rr0 = 0; rr0 < 2; ++rr0) {
        const int rr = pl + rr0 * 4;
        float o = bo[h];
#pragma unroll
        for (int l = 0; l < HH; ++l) o = fmaf(Rl[rr][l], wo[l * HH + h], o);
        outf[(pblk + rr) * HH + h] = o;
    }
}

// ---------------------------------------------------------------------------
// pool partial: block = (batch, chunk of 8); sums 256 rows -> pp[batch][ch][64]
// ---------------------------------------------------------------------------
__global__ __launch_bounds__(256) void pool_partial_kernel(const float* __restrict__ feat,
                                                           float* __restrict__ pp) {
    __shared__ float part[4][HH];
    const int batch = blockIdx.x >> 3;
    const int chk = blockIdx.x & 7;
    const int tid = threadIdx.x;
    const int h = tid & 63;
    const int sub = tid >> 6;
    float s = 0.f;
    const float* fp = feat + ((long)batch * NN + chk * 256 + sub * 64) * HH + h;
    for (int n = 0; n < 64; ++n) s += fp[(long)n * HH];
    part[sub][h] = s;
    __syncthreads();
    if (tid < HH)
        pp[(batch * 8 + chk) * HH + h] = part[0][h] + part[1][h] + part[2][h] + part[3][h];
}

// ---------------------------------------------------------------------------
// head: g[b] = mean; out[b] = relu(g@fw1+fb1)@fw2+fb2. Block = batch.
// ---------------------------------------------------------------------------
__global__ __launch_bounds__(256) void head_kernel(const float* __restrict__ pp,
                                                   const float* __restrict__ fw1,
                                                   const float* __restrict__ fb1,
                                                   const float* __restrict__ fw2,
                                                   const float* __restrict__ fb2,
                                                   float* __restrict__ out) {
    __shared__ float g[HH];
    __shared__ float tl[HH];
    const int b = blockIdx.x;
    const int tid = threadIdx.x;
    if (tid < HH) {
        float s = 0.f;
#pragma unroll
        for (int c = 0; c < 8; ++c) s += pp[(b * 8 + c) * HH + tid];
        g[tid] = s * (1.f / NN);
    }
    __syncthreads();
    if (tid < HH) {
        float a = fb1[tid];
#pragma unroll
        for (int l = 0; l < HH; ++l) a = fmaf(g[l], fw1[l * HH + tid], a);
        tl[tid] = fmaxf(a, 0.f);
    }
    __syncthreads();
    if (tid < OUTC) {
        float o = fb2[tid];
#pragma unroll
        for (int l = 0; l < HH; ++l) o = fmaf(tl[l], fw2[l * OUTC + tid], o);
        out[(long)b * OUTC + tid] = o;
    }
}

// ---------------------------------------------------------------------------
extern "C" void kernel_launch(void* const* d_in, const int* in_sizes, int n_in,
                              void* d_out, int out_size, void* d_ws, size_t ws_size,
                              hipStream_t stream) {
    const float* x    = (const float*)d_in[0];
    const float* w1_0 = (const float*)d_in[1];
    const float* b1_0 = (const float*)d_in[2];
    const float* wo_0 = (const float*)d_in[3];
    const float* bo_0 = (const float*)d_in[4];
    const float* w1_1 = (const float*)d_in[5];
    const float* b1_1 = (const float*)d_in[6];
    const float* wo_1 = (const float*)d_in[7];
    const float* bo_1 = (const float*)d_in[8];
    const float* w1_2 = (const float*)d_in[9];
    const float* b1_2 = (const float*)d_in[10];
    const float* wo_2 = (const float*)d_in[11];
    const float* bo_2 = (const float*)d_in[12];
    const float* fw1  = (const float*)d_in[13];
    const float* fb1  = (const float*)d_in[14];
    const float* fw2  = (const float*)d_in[15];
    const float* fb2  = (const float*)d_in[16];
    float* out = (float*)d_out;

    // workspace layout (floats)
    float* featA = (float*)d_ws;
    float* featB = featA + (long)BN * HH;
    float* Pb    = featB + (long)BN * HH;
    float* Qb    = Pb + (long)BN * HH;
    float* sqb   = Qb + (long)BN * HH;
    unsigned short* idx32 = (unsigned short*)(sqb + BN);     // BN x 32 u16
    float* ppb   = (float*)(idx32 + (long)BN * 32);          // 32 x 8 x 64

    // bf16 feature mirrors alias the OPPOSITE feature buffer (consumed by the
    // filter before rescore_gather rewrites that buffer)
    __bf16* fbf1 = (__bf16*)featB;   // layer 1 (featB rewritten after filter)
    __bf16* fbf2 = (__bf16*)featA;   // layer 2 (featA rewritten after filter)

    // ---- layer 0 (D=3, exact fp32 kNN) ----
    prep3_kernel<<<BN / 4, 256, 0, stream>>>(x, w1_0, b1_0, sqb, Pb, Qb);
    knn3_filter_kernel<<<BB * 32, 256, 0, stream>>>(x, sqb, idx32);
    rescore_gather_kernel<3><<<BN / 8, 256, 0, stream>>>(x, sqb, idx32, Pb, Qb, wo_0, bo_0, featA);

    // ---- layer 1 (D=64) ----
    prep64_kernel<<<BN / 4, 256, 0, stream>>>(featA, w1_1, b1_1, fbf1, sqb, Pb, Qb);
    knn_filter_kernel<<<BB * 32, 256, 0, stream>>>(fbf1, sqb, idx32);
    rescore_gather_kernel<64><<<BN / 8, 256, 0, stream>>>(featA, sqb, idx32, Pb, Qb, wo_1, bo_1, featB);

    // ---- layer 2 (D=64) ----
    prep64_kernel<<<BN / 4, 256, 0, stream>>>(featB, w1_2, b1_2, fbf2, sqb, Pb, Qb);
    knn_filter_kernel<<<BB * 32, 256, 0, stream>>>(fbf2, sqb, idx32);
    rescore_gather_kernel<64><<<BN / 8, 256, 0, stream>>>(featB, sqb, idx32, Pb, Qb, wo_2, bo_2, featA);

    // ---- pool + head ----
    pool_partial_kernel<<<BB * 8, 256, 0, stream>>>(featA, ppb);
    head_kernel<<<BB, 256, 0, stream>>>(ppb, fw1, fb1, fw2, fb2, out);
}

// Round 9
// 744.716 us; speedup vs baseline: 19.2585x; 1.0809x over previous
//
#include <hip/hip_runtime.h>

// Problem constants
#define BB 32
#define NN 2048
#define FF 3
#define HH 64
#define OUTC 128
#define KK 16
#define BN (BB * NN)   // 65536 points

typedef __attribute__((ext_vector_type(8))) __bf16 bf16x8;
typedef __attribute__((ext_vector_type(4))) float f32x4;

// Pack d2 + candidate index into one sortable u32:
// high 21 bits = monotone(float d2) truncated, low 11 bits = idx (NN=2^11).
__device__ __forceinline__ unsigned int packkey(float d2, unsigned int m) {
    unsigned int bb = __builtin_bit_cast(unsigned int, d2);
    unsigned int msk = (unsigned int)((int)bb >> 31);
    unsigned int srt = bb ^ (msk | 0x80000000u);
    return (srt & 0xFFFFF800u) | m;
}

__device__ __forceinline__ void ce(unsigned int& a, unsigned int& b) {
    unsigned int lo = a < b ? a : b;
    unsigned int hi = a < b ? b : a;
    a = lo; b = hi;
}

// Sort 16 keys ascending — Batcher odd-even mergesort (63 CE, branchless).
__device__ __forceinline__ void sort16(unsigned int k[16]) {
#pragma unroll
    for (int p = 1; p < 16; p <<= 1)
#pragma unroll
        for (int q = p; q >= 1; q >>= 1)
#pragma unroll
            for (int j = q % p; j + q < 16; j += 2 * q)
#pragma unroll
                for (int i = 0; i < q; ++i) {
                    int x = i + j, y = i + j + q;
                    if (y < 16 && (x / (2 * p) == y / (2 * p))) ce(k[x], k[y]);
                }
}

// keys (sorted asc) <- lowest-16 of union(keys, nk), nk sorted asc.
__device__ __forceinline__ void merge16(unsigned int keys[16], const unsigned int nk[16]) {
    unsigned int t[16];
#pragma unroll
    for (int i = 0; i < 16; ++i) {
        unsigned int b = nk[15 - i];
        t[i] = keys[i] < b ? keys[i] : b;
    }
#pragma unroll
    for (int d = 8; d >= 1; d >>= 1)
#pragma unroll
        for (int i = 0; i < 16; ++i)
            if ((i & d) == 0) ce(t[i], t[i ^ d]);
#pragma unroll
    for (int i = 0; i < 16; ++i) keys[i] = t[i];
}

// ---------------------------------------------------------------------------
// prep3 (layer 0): sq + P/Q from x (D=3). Wave = one row (64 h-lanes).
// ---------------------------------------------------------------------------
__global__ __launch_bounds__(256) void prep3_kernel(const float* __restrict__ x,
                                                    const float* __restrict__ w1,
                                                    const float* __restrict__ b1,
                                                    float* __restrict__ sqo,
                                                    float* __restrict__ P,
                                                    float* __restrict__ Q) {
    const int tid = threadIdx.x;
    const int h = tid & 63;
    const int pl = tid >> 6;
    const long p = (long)blockIdx.x * 4 + pl;
    const float* fp = x + p * 3;
    const float f0 = fp[0], f1 = fp[1], f2 = fp[2];
    if (h == 0) sqo[p] = f0 * f0 + f1 * f1 + f2 * f2;
    float accp = 0.f, accq = 0.f;
    const float fv[3] = {f0, f1, f2};
#pragma unroll
    for (int d = 0; d < 3; ++d) {
        float wa = w1[d * HH + h];
        float wb = w1[(3 + d) * HH + h];
        accp = fmaf(fv[d], wa - wb, accp);
        accq = fmaf(fv[d], wb, accq);
    }
    P[p * HH + h] = accp + b1[h];
    Q[p * HH + h] = accq;
}

// ---------------------------------------------------------------------------
// prep64 (layers 1,2): fused bf16-convert + sq + P/Q. Wave = one row.
// ---------------------------------------------------------------------------
__global__ __launch_bounds__(256) void prep64_kernel(const float* __restrict__ feat,
                                                     const float* __restrict__ w1,
                                                     const float* __restrict__ b1,
                                                     __bf16* __restrict__ fbf,
                                                     float* __restrict__ sqo,
                                                     float* __restrict__ P,
                                                     float* __restrict__ Q) {
    const int tid = threadIdx.x;
    const int h = tid & 63;
    const int pl = tid >> 6;
    const long p = (long)blockIdx.x * 4 + pl;
    const float* fp = feat + p * HH;

    // lane-varying element: bf16 convert + squared-sum reduce
    float fvh = fp[h];
    fbf[p * HH + h] = (__bf16)fvh;
    float s = fvh * fvh;
    s += __shfl_xor(s, 1);
    s += __shfl_xor(s, 2);
    s += __shfl_xor(s, 4);
    s += __shfl_xor(s, 8);
    s += __shfl_xor(s, 16);
    s += __shfl_xor(s, 32);
    if (h == 0) sqo[p] = s;

    float accp = 0.f, accq = 0.f;
#pragma unroll
    for (int d = 0; d < HH; ++d) {
        float fv = fp[d];            // wave-uniform -> scalar load
        float wa = w1[d * HH + h];
        float wb = w1[(HH + d) * HH + h];
        accp = fmaf(fv, wa - wb, accp);
        accq = fmaf(fv, wb, accq);
    }
    P[p * HH + h] = accp + b1[h];
    Q[p * HH + h] = accq;
}

// ---------------------------------------------------------------------------
// Layer-0 kNN filter (D=3, fp32 scores, exact path preserved): block = 64
// rows x 2048 cands. Register prefetch; XCD-pinned batches; u16 output.
// ---------------------------------------------------------------------------
__global__ __launch_bounds__(256) void knn3_filter_kernel(const float* __restrict__ x,
                                                          const float* __restrict__ sq,
                                                          unsigned short* __restrict__ idx32) {
    __shared__ float4 lds_c[256];
    __shared__ unsigned int Km[64 * 68];
    const int tid = threadIdx.x;
    // batch->XCD pinning: blocks with blockIdx%8==x land on XCD x (heuristic)
    const int xcd = blockIdx.x & 7;
    const int ii = blockIdx.x >> 3;          // 0..127
    const int b = xcd + 8 * (ii >> 5);       // 4 batches per XCD
    const int rg = ii & 31;
    const long pbase = (long)b * NN;
    const int r = tid >> 2, slot = tid & 3;
    const int row = rg * 64 + r;

    const float* rp = x + (pbase + row) * 3;
    const float xr0 = rp[0], xr1 = rp[1], xr2 = rp[2];

    unsigned int keys[KK];
#pragma unroll
    for (int j = 0; j < KK; ++j) keys[j] = 0xFFFFFFFFu;

    // preload tile 0
    float c0, c1, c2, c3;
    {
        const float* cp = x + (pbase + tid) * 3;
        c0 = cp[0]; c1 = cp[1]; c2 = cp[2]; c3 = sq[pbase + tid];
    }

    for (int t = 0; t < NN / 256; ++t) {
        __syncthreads();                      // prev selection done reading lds_c
        lds_c[tid] = make_float4(c0, c1, c2, c3);
        __syncthreads();                      // tile ready
        if (t < NN / 256 - 1) {               // prefetch next tile (hidden by selection)
            const int m = (t + 1) * 256 + tid;
            const float* cp = x + (pbase + m) * 3;
            c0 = cp[0]; c1 = cp[1]; c2 = cp[2]; c3 = sq[pbase + m];
        }
        const int cbase = slot * 64;
#pragma unroll
        for (int bb = 0; bb < 4; ++bb) {
            unsigned int nk[16];
#pragma unroll
            for (int cc = 0; cc < 16; ++cc) {
                float4 v = lds_c[cbase + bb * 16 + cc];
                float dot = fmaf(xr0, v.x, fmaf(xr1, v.y, xr2 * v.z));
                float d2 = fmaf(-2.0f, dot, v.w);   // sq_row dropped (rank-invariant)
                nk[cc] = packkey(d2, (unsigned int)(t * 256 + cbase + bb * 16 + cc));
            }
            sort16(nk);
            merge16(keys, nk);
        }
    }

    // merge: 4 sorted lists -> 2 x (lowest-16 of half-union) = 32 cands
    {
        uint4* kw = (uint4*)&Km[r * 68 + slot * 16];
#pragma unroll
        for (int q = 0; q < 4; ++q)
            kw[q] = make_uint4(keys[4 * q], keys[4 * q + 1], keys[4 * q + 2], keys[4 * q + 3]);
    }
    __syncthreads();
    if (slot < 2) {
        const unsigned int* k0 = &Km[r * 68 + slot * 32];
        const unsigned int* k1 = k0 + 16;
        unsigned short ms[16];
#pragma unroll
        for (int j = 0; j < 16; ++j) {
            unsigned int a = k0[j], bv = k1[15 - j];
            ms[j] = (unsigned short)((a < bv ? a : bv) & 0x7FFu);
        }
        uint4* op = (uint4*)(idx32 + ((pbase + row) * 32 + slot * 16));
        op[0] = ((const uint4*)ms)[0];
        op[1] = ((const uint4*)ms)[1];
    }
}

// ---------------------------------------------------------------------------
// bf16-MFMA filter (D=64): block = 64 rows x 2048 cands. Register prefetch,
// XCD-pinned batches, u16 output.
// ---------------------------------------------------------------------------
#define APAD 80   // LDS row stride (bf16 elems)
#define DPAD 68   // key-tile stride (u32)

__global__ __launch_bounds__(256) void knn_filter_kernel(const __bf16* __restrict__ fbf,
                                                         const float* __restrict__ sq,
                                                         unsigned short* __restrict__ idx32) {
    __shared__ __align__(16) __bf16 Ab[64 * APAD];
    __shared__ __align__(16) __bf16 Bb[64 * APAD];
    __shared__ __align__(16) unsigned int Dt[64 * DPAD];
    __shared__ float SqC[64];

    const int tid = threadIdx.x;
    const int xcd = blockIdx.x & 7;
    const int ii = blockIdx.x >> 3;          // 0..127
    const int b = xcd + 8 * (ii >> 5);       // 4 batches per XCD
    const int rg = ii & 31;
    const long pbase = (long)b * NN;
    const int row0 = rg * 64;
    const int ci = tid >> 2, ch = tid & 3;

    // stage A (64 rows x 64 dims bf16)
    {
        const __bf16* src = fbf + (pbase + row0 + ci) * 64 + ch * 16;
        uint4 v0 = *(const uint4*)src;
        uint4 v1 = *(const uint4*)(src + 8);
        *(uint4*)&Ab[ci * APAD + ch * 16] = v0;
        *(uint4*)&Ab[ci * APAD + ch * 16 + 8] = v1;
    }
    __syncthreads();

    const int wv = tid >> 6, ln = tid & 63;
    const int n16 = ln & 15, quad = ln >> 4;
    bf16x8 af0, af1;
    {
        const __bf16* ap = &Ab[(wv * 16 + n16) * APAD + quad * 8];
        af0 = *(const bf16x8*)ap;
        af1 = *(const bf16x8*)(ap + 32);
    }

    const int r = tid >> 2, slot = tid & 3;
    unsigned int keys[KK];
#pragma unroll
    for (int j = 0; j < KK; ++j) keys[j] = 0xFFFFFFFFu;

    // preload tile 0 into registers
    uint4 pv0, pv1;
    float psq;
    {
        const __bf16* src = fbf + (pbase + ci) * 64 + ch * 16;
        pv0 = *(const uint4*)src;
        pv1 = *(const uint4*)(src + 8);
        psq = (tid < 64) ? sq[pbase + tid] : 0.f;
    }

    for (int t = 0; t < NN / 64; ++t) {
        // write staged tile (registers -> LDS); safe: all Bb/SqC readers done
        *(uint4*)&Bb[ci * APAD + ch * 16] = pv0;
        *(uint4*)&Bb[ci * APAD + ch * 16 + 8] = pv1;
        if (tid < 64) SqC[tid] = psq;
        __syncthreads();   // barrier 1: Bb/SqC ready; prev selection done with Dt

        // MFMA phase: wave wv computes rows [wv*16, wv*16+16) x all 64 cands
#pragma unroll
        for (int ct = 0; ct < 4; ++ct) {
            const __bf16* bp = &Bb[(ct * 16 + n16) * APAD + quad * 8];
            bf16x8 bf0 = *(const bf16x8*)bp;
            bf16x8 bf1 = *(const bf16x8*)(bp + 32);
            f32x4 acc = {0.f, 0.f, 0.f, 0.f};
            acc = __builtin_amdgcn_mfma_f32_16x16x32_bf16(af0, bf0, acc, 0, 0, 0);
            acc = __builtin_amdgcn_mfma_f32_16x16x32_bf16(af1, bf1, acc, 0, 0, 0);
            const int ccol = ct * 16 + n16;
            const float sqc = SqC[ccol];
            const unsigned int m = (unsigned int)(t * 64 + ccol);
#pragma unroll
            for (int rr = 0; rr < 4; ++rr) {
                const int rrow = wv * 16 + quad * 4 + rr;
                Dt[rrow * DPAD + ccol] = packkey(fmaf(-2.0f, acc[rr], sqc), m);
            }
        }
        __syncthreads();   // barrier 2: Dt ready, Bb reads done

        // prefetch next tile into registers (latency hidden by selection)
        if (t < NN / 64 - 1) {
            const __bf16* src = fbf + (pbase + (long)(t + 1) * 64 + ci) * 64 + ch * 16;
            pv0 = *(const uint4*)src;
            pv1 = *(const uint4*)(src + 8);
            if (tid < 64) psq = sq[pbase + (t + 1) * 64 + tid];
        }

        // selection: thread (r, slot) sorts its 16 keys, merges into top-16
        {
            const uint4* kp = (const uint4*)&Dt[r * DPAD + slot * 16];
            unsigned int nk[16];
#pragma unroll
            for (int q = 0; q < 4; ++q) {
                uint4 kv = kp[q];
                nk[4 * q + 0] = kv.x; nk[4 * q + 1] = kv.y;
                nk[4 * q + 2] = kv.z; nk[4 * q + 3] = kv.w;
            }
            sort16(nk);
            merge16(keys, nk);
        }
    }

    // merge: reuse Dt as staging; 4 sorted lists -> 32-cand union superset
    __syncthreads();
    {
        uint4* kw = (uint4*)&Dt[r * DPAD + slot * 16];
#pragma unroll
        for (int q = 0; q < 4; ++q)
            kw[q] = make_uint4(keys[4 * q], keys[4 * q + 1], keys[4 * q + 2], keys[4 * q + 3]);
    }
    __syncthreads();
    if (slot < 2) {
        const unsigned int* k0 = &Dt[r * DPAD + slot * 32];
        const unsigned int* k1 = k0 + 16;
        unsigned short ms[16];
#pragma unroll
        for (int j = 0; j < 16; ++j) {
            unsigned int a = k0[j], bv = k1[15 - j];
            ms[j] = (unsigned short)((a < bv ? a : bv) & 0x7FFu);
        }
        uint4* op = (uint4*)(idx32 + ((pbase + row0 + r) * 32 + slot * 16));
        op[0] = ((const uint4*)ms)[0];
        op[1] = ((const uint4*)ms)[1];
    }
}

// ---------------------------------------------------------------------------
// Fused rescore + gather + edge-MLP, XCD-pinned batches. Block = 8 rows.
// D=64 gather uses a coalescing-optimal lane layout: 4 consecutive lanes read
// 4 consecutive 16B chunks of ONE candidate-row cache line (16 line-requests
// per instruction instead of 64).
// ---------------------------------------------------------------------------
template <int D>
__global__ __launch_bounds__(256) void rescore_gather_kernel(const float* __restrict__ feat,
                                                             const float* __restrict__ sq,
                                                             const unsigned short* __restrict__ idx32,
                                                             const float* __restrict__ P,
                                                             const float* __restrict__ Q,
                                                             const float* __restrict__ wo,
                                                             const float* __restrict__ bo,
                                                             float* __restrict__ outf) {
    __shared__ float rowf[8][D];
    __shared__ float Sc[8][32];
    __shared__ int Ji[8][32];
    __shared__ float Sq32[8][32];
    __shared__ int Li[8][KK];
    __shared__ float Rl[8][HH];
    const int tid = threadIdx.x;
    const int w = tid >> 6, ln = tid & 63;
    const int rw = ln >> 5, c = ln & 31;
    // batch->XCD pinning: each XCD's L2 sees only 4 batches' gather set
    const int xcd = blockIdx.x & 7;
    const int ii = blockIdx.x >> 3;            // 0..1023
    const int batch = xcd + 8 * (ii >> 8);     // 4 batches per XCD
    const int rb = ii & 255;
    const long pbase = (long)batch * NN;
    const long pblk = pbase + (long)rb * 8;
    const long p = pblk + w * 2 + rw;
    const int row_ = w * 2 + rw;

    for (int i = tid; i < 8 * D; i += 256) rowf[i / D][i % D] = feat[pblk * D + i];
    {
        const int j0 = (int)idx32[p * 32 + c];
        Ji[row_][c] = j0;
        Sq32[row_][c] = sq[pbase + j0];
    }
    __syncthreads();

    if constexpr (D == 64) {
        // gather + dot: lane = (cg, e); cg = cand-in-pass, e = 16B slot in line
        const int cg = ln >> 2, e = ln & 3;
#pragma unroll
        for (int rr = 0; rr < 2; ++rr) {
#pragma unroll
            for (int pp = 0; pp < 2; ++pp) {
                const int row = w * 2 + rr;
                const int cand = pp * 16 + cg;
                const int jj = Ji[row][cand];
                const float* cb = feat + (pbase + jj) * 64;
                float part = 0.f;
#pragma unroll
                for (int blk = 0; blk < 4; ++blk) {
                    float4 cv = *(const float4*)(cb + blk * 16 + e * 4);
                    float4 rv = *(const float4*)&rowf[row][blk * 16 + e * 4];
                    part = fmaf(rv.x, cv.x, part);
                    part = fmaf(rv.y, cv.y, part);
                    part = fmaf(rv.z, cv.z, part);
                    part = fmaf(rv.w, cv.w, part);
                }
                part += __shfl_xor(part, 1);
                part += __shfl_xor(part, 2);
                if (e == 0) Sc[row][cand] = fmaf(-2.0f, part, Sq32[row][cand]);
            }
        }
    } else {
        const int jj = Ji[row_][c];
        const float* cp = feat + (pbase + jj) * 3;
        float dot = fmaf(rowf[row_][0], cp[0],
                    fmaf(rowf[row_][1], cp[1], rowf[row_][2] * cp[2]));
        Sc[row_][c] = fmaf(-2.0f, dot, Sq32[row_][c]);
    }
    __syncthreads();

    // rank: exact lexicographic (score, j) over the 32 candidates (LDS broadcast)
    {
        const float score = Sc[row_][c];
        const int j = Ji[row_][c];
        int rank = 0;
#pragma unroll
        for (int m = 0; m < 32; ++m) {
            float dm = Sc[row_][m];
            int jm = Ji[row_][m];
            rank += (dm < score || (dm == score && jm < j)) ? 1 : 0;
        }
        if (rank < KK) Li[row_][rank] = j;
    }
    __syncthreads();

    // Phase 2: gather + MLP for the 8 rows
    const int h = tid & 63, pl = tid >> 6;
#pragma unroll
    for (int rr0 = 0; rr0 < 2; ++rr0) {
        const int rr = pl + rr0 * 4;
        const long pp = pblk + rr;
        const float Pv = P[pp * HH + h];
        float acc = 0.f;
#pragma unroll
        for (int k = 0; k < KK; ++k) {
            int j2 = Li[rr][k];
            acc += fmaxf(Pv + Q[(pbase + j2) * HH + h], 0.f);
        }
        Rl[rr][h] = acc * (1.f / KK);
    }
    __syncthreads();
#pragma unroll
    for (int rr0 = 0; rr0 < 2; ++rr0) {
        const int rr = pl + rr0 * 4;
        float o = bo[h];
#pragma unroll
        for (int l = 0; l < HH; ++l) o = fmaf(Rl[rr][l], wo[l * HH + h], o);
        outf[(pblk + rr) * HH + h] = o;
    }
}

// ---------------------------------------------------------------------------
// pool partial: block = (batch, chunk of 8); sums 256 rows -> pp[batch][ch][64]
// ---------------------------------------------------------------------------
__global__ __launch_bounds__(256) void pool_partial_kernel(const float* __restrict__ feat,
                                                           float* __restrict__ pp) {
    __shared__ float part[4][HH];
    const int batch = blockIdx.x >> 3;
    const int chk = blockIdx.x & 7;
    const int tid = threadIdx.x;
    const int h = tid & 63;
    const int sub = tid >> 6;
    float s = 0.f;
    const float* fp = feat + ((long)batch * NN + chk * 256 + sub * 64) * HH + h;
    for (int n = 0; n < 64; ++n) s += fp[(long)n * HH];
    part[sub][h] = s;
    __syncthreads();
    if (tid < HH)
        pp[(batch * 8 + chk) * HH + h] = part[0][h] + part[1][h] + part[2][h] + part[3][h];
}

// ---------------------------------------------------------------------------
// head: g[b] = mean; out[b] = relu(g@fw1+fb1)@fw2+fb2. Block = batch.
// ---------------------------------------------------------------------------
__global__ __launch_bounds__(256) void head_kernel(const float* __restrict__ pp,
                                                   const float* __restrict__ fw1,
                                                   const float* __restrict__ fb1,
                                                   const float* __restrict__ fw2,
                                                   const float* __restrict__ fb2,
                                                   float* __restrict__ out) {
    __shared__ float g[HH];
    __shared__ float tl[HH];
    const int b = blockIdx.x;
    const int tid = threadIdx.x;
    if (tid < HH) {
        float s = 0.f;
#pragma unroll
        for (int c = 0; c < 8; ++c) s += pp[(b * 8 + c) * HH + tid];
        g[tid] = s * (1.f / NN);
    }
    __syncthreads();
    if (tid < HH) {
        float a = fb1[tid];
#pragma unroll
        for (int l = 0; l < HH; ++l) a = fmaf(g[l], fw1[l * HH + tid], a);
        tl[tid] = fmaxf(a, 0.f);
    }
    __syncthreads();
    if (tid < OUTC) {
        float o = fb2[tid];
#pragma unroll
        for (int l = 0; l < HH; ++l) o = fmaf(tl[l], fw2[l * OUTC + tid], o);
        out[(long)b * OUTC + tid] = o;
    }
}

// ---------------------------------------------------------------------------
extern "C" void kernel_launch(void* const* d_in, const int* in_sizes, int n_in,
                              void* d_out, int out_size, void* d_ws, size_t ws_size,
                              hipStream_t stream) {
    const float* x    = (const float*)d_in[0];
    const float* w1_0 = (const float*)d_in[1];
    const float* b1_0 = (const float*)d_in[2];
    const float* wo_0 = (const float*)d_in[3];
    const float* bo_0 = (const float*)d_in[4];
    const float* w1_1 = (const float*)d_in[5];
    const float* b1_1 = (const float*)d_in[6];
    const float* wo_1 = (const float*)d_in[7];
    const float* bo_1 = (const float*)d_in[8];
    const float* w1_2 = (const float*)d_in[9];
    const float* b1_2 = (const float*)d_in[10];
    const float* wo_2 = (const float*)d_in[11];
    const float* bo_2 = (const float*)d_in[12];
    const float* fw1  = (const float*)d_in[13];
    const float* fb1  = (const float*)d_in[14];
    const float* fw2  = (const float*)d_in[15];
    const float* fb2  = (const float*)d_in[16];
    float* out = (float*)d_out;

    // workspace layout (floats)
    float* featA = (float*)d_ws;
    float* featB = featA + (long)BN * HH;
    float* Pb    = featB + (long)BN * HH;
    float* Qb    = Pb + (long)BN * HH;
    float* sqb   = Qb + (long)BN * HH;
    unsigned short* idx32 = (unsigned short*)(sqb + BN);     // BN x 32 u16
    float* ppb   = (float*)(idx32 + (long)BN * 32);          // 32 x 8 x 64

    // bf16 feature mirrors alias the OPPOSITE feature buffer (consumed by the
    // filter before rescore_gather rewrites that buffer)
    __bf16* fbf1 = (__bf16*)featB;   // layer 1 (featB rewritten after filter)
    __bf16* fbf2 = (__bf16*)featA;   // layer 2 (featA rewritten after filter)

    // ---- layer 0 (D=3, exact fp32 kNN) ----
    prep3_kernel<<<BN / 4, 256, 0, stream>>>(x, w1_0, b1_0, sqb, Pb, Qb);
    knn3_filter_kernel<<<BB * 32, 256, 0, stream>>>(x, sqb, idx32);
    rescore_gather_kernel<3><<<BN / 8, 256, 0, stream>>>(x, sqb, idx32, Pb, Qb, wo_0, bo_0, featA);

    // ---- layer 1 (D=64) ----
    prep64_kernel<<<BN / 4, 256, 0, stream>>>(featA, w1_1, b1_1, fbf1, sqb, Pb, Qb);
    knn_filter_kernel<<<BB * 32, 256, 0, stream>>>(fbf1, sqb, idx32);
    rescore_gather_kernel<64><<<BN / 8, 256, 0, stream>>>(featA, sqb, idx32, Pb, Qb, wo_1, bo_1, featB);

    // ---- layer 2 (D=64) ----
    prep64_kernel<<<BN / 4, 256, 0, stream>>>(featB, w1_2, b1_2, fbf2, sqb, Pb, Qb);
    knn_filter_kernel<<<BB * 32, 256, 0, stream>>>(fbf2, sqb, idx32);
    rescore_gather_kernel<64><<<BN / 8, 256, 0, stream>>>(featB, sqb, idx32, Pb, Qb, wo_2, bo_2, featA);

    // ---- pool + head ----
    pool_partial_kernel<<<BB * 8, 256, 0, stream>>>(featA, ppb);
    head_kernel<<<BB, 256, 0, stream>>>(ppb, fw1, fb1, fw2, fb2, out);
}

// Round 10
// 614.490 us; speedup vs baseline: 23.3399x; 1.2119x over previous
//
#include <hip/hip_runtime.h>

// Problem constants
#define BB 32
#define NN 2048
#define FF 3
#define HH 64
#define OUTC 128
#define KK 16
#define BN (BB * NN)   // 65536 points

typedef __attribute__((ext_vector_type(8))) __bf16 bf16x8;
typedef __attribute__((ext_vector_type(4))) float f32x4;

// Pack d2 + candidate index into one sortable u32:
// high 21 bits = monotone(float d2) truncated, low 11 bits = idx (NN=2^11).
__device__ __forceinline__ unsigned int packkey(float d2, unsigned int m) {
    unsigned int bb = __builtin_bit_cast(unsigned int, d2);
    unsigned int msk = (unsigned int)((int)bb >> 31);
    unsigned int srt = bb ^ (msk | 0x80000000u);
    return (srt & 0xFFFFF800u) | m;
}

__device__ __forceinline__ void ce(unsigned int& a, unsigned int& b) {
    unsigned int lo = a < b ? a : b;
    unsigned int hi = a < b ? b : a;
    a = lo; b = hi;
}

// Sort 16 keys ascending — Batcher odd-even mergesort (63 CE, branchless).
__device__ __forceinline__ void sort16(unsigned int k[16]) {
#pragma unroll
    for (int p = 1; p < 16; p <<= 1)
#pragma unroll
        for (int q = p; q >= 1; q >>= 1)
#pragma unroll
            for (int j = q % p; j + q < 16; j += 2 * q)
#pragma unroll
                for (int i = 0; i < q; ++i) {
                    int x = i + j, y = i + j + q;
                    if (y < 16 && (x / (2 * p) == y / (2 * p))) ce(k[x], k[y]);
                }
}

// keys (sorted asc) <- lowest-16 of union(keys, nk), nk sorted asc.
__device__ __forceinline__ void merge16(unsigned int keys[16], const unsigned int nk[16]) {
    unsigned int t[16];
#pragma unroll
    for (int i = 0; i < 16; ++i) {
        unsigned int b = nk[15 - i];
        t[i] = keys[i] < b ? keys[i] : b;
    }
#pragma unroll
    for (int d = 8; d >= 1; d >>= 1)
#pragma unroll
        for (int i = 0; i < 16; ++i)
            if ((i & d) == 0) ce(t[i], t[i ^ d]);
#pragma unroll
    for (int i = 0; i < 16; ++i) keys[i] = t[i];
}

// ---------------------------------------------------------------------------
// prep3 (layer 0): sq + P/Q from x (D=3). Wave = one row (64 h-lanes).
// ---------------------------------------------------------------------------
__global__ __launch_bounds__(256) void prep3_kernel(const float* __restrict__ x,
                                                    const float* __restrict__ w1,
                                                    const float* __restrict__ b1,
                                                    float* __restrict__ sqo,
                                                    float* __restrict__ P,
                                                    float* __restrict__ Q) {
    const int tid = threadIdx.x;
    const int h = tid & 63;
    const int pl = tid >> 6;
    const long p = (long)blockIdx.x * 4 + pl;
    const float* fp = x + p * 3;
    const float f0 = fp[0], f1 = fp[1], f2 = fp[2];
    if (h == 0) sqo[p] = f0 * f0 + f1 * f1 + f2 * f2;
    float accp = 0.f, accq = 0.f;
    const float fv[3] = {f0, f1, f2};
#pragma unroll
    for (int d = 0; d < 3; ++d) {
        float wa = w1[d * HH + h];
        float wb = w1[(3 + d) * HH + h];
        accp = fmaf(fv[d], wa - wb, accp);
        accq = fmaf(fv[d], wb, accq);
    }
    P[p * HH + h] = accp + b1[h];
    Q[p * HH + h] = accq;
}

// ---------------------------------------------------------------------------
// prep64 (layers 1,2): fused bf16-convert + sq + P/Q. Block = 64 rows.
// Weights live in 128 VGPRs per lane (loaded once); rows staged in LDS and
// broadcast via uniform-address ds_read_b128. Split accumulators break the
// fma dependence chain.
// ---------------------------------------------------------------------------
__global__ __launch_bounds__(256) void prep64_kernel(const float* __restrict__ feat,
                                                     const float* __restrict__ w1,
                                                     const float* __restrict__ b1,
                                                     __bf16* __restrict__ fbf,
                                                     float* __restrict__ sqo,
                                                     float* __restrict__ P,
                                                     float* __restrict__ Q) {
    __shared__ float rows[64 * HH];   // 16 KB
    const int tid = threadIdx.x;
    const int h = tid & 63;
    const int wv = tid >> 6;
    const long row0 = (long)blockIdx.x * 64;

    // loop-invariant weights -> VGPRs (coalesced, L1-resident after block 0)
    float wdiff[64], wbv[64];
#pragma unroll
    for (int d = 0; d < 64; ++d) {
        float wa = w1[d * HH + h];
        float wb_ = w1[(HH + d) * HH + h];
        wdiff[d] = wa - wb_;
        wbv[d] = wb_;
    }
    const float bv = b1[h];

    // stage 64 rows (coalesced float4)
    {
        const float4* src = (const float4*)(feat + row0 * HH);
        float4* dst = (float4*)rows;
#pragma unroll
        for (int i = 0; i < 4; ++i) dst[tid + 256 * i] = src[tid + 256 * i];
    }
    __syncthreads();

    // each wave handles 16 rows
    for (int r = wv * 16; r < wv * 16 + 16; ++r) {
        const long p = row0 + r;
        // transpose read (stride-1 per lane): bf16 convert + sq reduce
        float fvh = rows[r * HH + h];
        fbf[p * HH + h] = (__bf16)fvh;
        float s = fvh * fvh;
        s += __shfl_xor(s, 1);
        s += __shfl_xor(s, 2);
        s += __shfl_xor(s, 4);
        s += __shfl_xor(s, 8);
        s += __shfl_xor(s, 16);
        s += __shfl_xor(s, 32);
        if (h == 0) sqo[p] = s;

        float ap0 = 0.f, ap1 = 0.f, aq0 = 0.f, aq1 = 0.f;
#pragma unroll
        for (int d4 = 0; d4 < 16; ++d4) {
            float4 fv = *(const float4*)&rows[r * HH + d4 * 4];   // uniform -> broadcast
            ap0 = fmaf(fv.x, wdiff[4 * d4 + 0], ap0);
            aq0 = fmaf(fv.x, wbv[4 * d4 + 0], aq0);
            ap1 = fmaf(fv.y, wdiff[4 * d4 + 1], ap1);
            aq1 = fmaf(fv.y, wbv[4 * d4 + 1], aq1);
            ap0 = fmaf(fv.z, wdiff[4 * d4 + 2], ap0);
            aq0 = fmaf(fv.z, wbv[4 * d4 + 2], aq0);
            ap1 = fmaf(fv.w, wdiff[4 * d4 + 3], ap1);
            aq1 = fmaf(fv.w, wbv[4 * d4 + 3], aq1);
        }
        P[p * HH + h] = (ap0 + ap1) + bv;
        Q[p * HH + h] = aq0 + aq1;
    }
}

// ---------------------------------------------------------------------------
// Layer-0 kNN filter (D=3, fp32 scores, exact path preserved): block = 64
// rows x 2048 cands. Register prefetch; XCD-pinned batches; u16 output.
// ---------------------------------------------------------------------------
__global__ __launch_bounds__(256) void knn3_filter_kernel(const float* __restrict__ x,
                                                          const float* __restrict__ sq,
                                                          unsigned short* __restrict__ idx32) {
    __shared__ float4 lds_c[256];
    __shared__ unsigned int Km[64 * 68];
    const int tid = threadIdx.x;
    // batch->XCD pinning: blocks with blockIdx%8==x land on XCD x (heuristic)
    const int xcd = blockIdx.x & 7;
    const int ii = blockIdx.x >> 3;          // 0..127
    const int b = xcd + 8 * (ii >> 5);       // 4 batches per XCD
    const int rg = ii & 31;
    const long pbase = (long)b * NN;
    const int r = tid >> 2, slot = tid & 3;
    const int row = rg * 64 + r;

    const float* rp = x + (pbase + row) * 3;
    const float xr0 = rp[0], xr1 = rp[1], xr2 = rp[2];

    unsigned int keys[KK];
#pragma unroll
    for (int j = 0; j < KK; ++j) keys[j] = 0xFFFFFFFFu;

    // preload tile 0
    float c0, c1, c2, c3;
    {
        const float* cp = x + (pbase + tid) * 3;
        c0 = cp[0]; c1 = cp[1]; c2 = cp[2]; c3 = sq[pbase + tid];
    }

    for (int t = 0; t < NN / 256; ++t) {
        __syncthreads();                      // prev selection done reading lds_c
        lds_c[tid] = make_float4(c0, c1, c2, c3);
        __syncthreads();                      // tile ready
        if (t < NN / 256 - 1) {               // prefetch next tile (hidden by selection)
            const int m = (t + 1) * 256 + tid;
            const float* cp = x + (pbase + m) * 3;
            c0 = cp[0]; c1 = cp[1]; c2 = cp[2]; c3 = sq[pbase + m];
        }
        const int cbase = slot * 64;
#pragma unroll
        for (int bb = 0; bb < 4; ++bb) {
            unsigned int nk[16];
#pragma unroll
            for (int cc = 0; cc < 16; ++cc) {
                float4 v = lds_c[cbase + bb * 16 + cc];
                float dot = fmaf(xr0, v.x, fmaf(xr1, v.y, xr2 * v.z));
                float d2 = fmaf(-2.0f, dot, v.w);   // sq_row dropped (rank-invariant)
                nk[cc] = packkey(d2, (unsigned int)(t * 256 + cbase + bb * 16 + cc));
            }
            sort16(nk);
            merge16(keys, nk);
        }
    }

    // merge: 4 sorted lists -> 2 x (lowest-16 of half-union) = 32 cands
    {
        uint4* kw = (uint4*)&Km[r * 68 + slot * 16];
#pragma unroll
        for (int q = 0; q < 4; ++q)
            kw[q] = make_uint4(keys[4 * q], keys[4 * q + 1], keys[4 * q + 2], keys[4 * q + 3]);
    }
    __syncthreads();
    if (slot < 2) {
        const unsigned int* k0 = &Km[r * 68 + slot * 32];
        const unsigned int* k1 = k0 + 16;
        unsigned short ms[16];
#pragma unroll
        for (int j = 0; j < 16; ++j) {
            unsigned int a = k0[j], bv = k1[15 - j];
            ms[j] = (unsigned short)((a < bv ? a : bv) & 0x7FFu);
        }
        uint4* op = (uint4*)(idx32 + ((pbase + row) * 32 + slot * 16));
        op[0] = ((const uint4*)ms)[0];
        op[1] = ((const uint4*)ms)[1];
    }
}

// ---------------------------------------------------------------------------
// bf16-MFMA filter (D=64): block = 64 rows x 2048 cands. Register prefetch,
// XCD-pinned batches, u16 output.
// ---------------------------------------------------------------------------
#define APAD 80   // LDS row stride (bf16 elems)
#define DPAD 68   // key-tile stride (u32)

__global__ __launch_bounds__(256) void knn_filter_kernel(const __bf16* __restrict__ fbf,
                                                         const float* __restrict__ sq,
                                                         unsigned short* __restrict__ idx32) {
    __shared__ __align__(16) __bf16 Ab[64 * APAD];
    __shared__ __align__(16) __bf16 Bb[64 * APAD];
    __shared__ __align__(16) unsigned int Dt[64 * DPAD];
    __shared__ float SqC[64];

    const int tid = threadIdx.x;
    const int xcd = blockIdx.x & 7;
    const int ii = blockIdx.x >> 3;          // 0..127
    const int b = xcd + 8 * (ii >> 5);       // 4 batches per XCD
    const int rg = ii & 31;
    const long pbase = (long)b * NN;
    const int row0 = rg * 64;
    const int ci = tid >> 2, ch = tid & 3;

    // stage A (64 rows x 64 dims bf16)
    {
        const __bf16* src = fbf + (pbase + row0 + ci) * 64 + ch * 16;
        uint4 v0 = *(const uint4*)src;
        uint4 v1 = *(const uint4*)(src + 8);
        *(uint4*)&Ab[ci * APAD + ch * 16] = v0;
        *(uint4*)&Ab[ci * APAD + ch * 16 + 8] = v1;
    }
    __syncthreads();

    const int wv = tid >> 6, ln = tid & 63;
    const int n16 = ln & 15, quad = ln >> 4;
    bf16x8 af0, af1;
    {
        const __bf16* ap = &Ab[(wv * 16 + n16) * APAD + quad * 8];
        af0 = *(const bf16x8*)ap;
        af1 = *(const bf16x8*)(ap + 32);
    }

    const int r = tid >> 2, slot = tid & 3;
    unsigned int keys[KK];
#pragma unroll
    for (int j = 0; j < KK; ++j) keys[j] = 0xFFFFFFFFu;

    // preload tile 0 into registers
    uint4 pv0, pv1;
    float psq;
    {
        const __bf16* src = fbf + (pbase + ci) * 64 + ch * 16;
        pv0 = *(const uint4*)src;
        pv1 = *(const uint4*)(src + 8);
        psq = (tid < 64) ? sq[pbase + tid] : 0.f;
    }

    for (int t = 0; t < NN / 64; ++t) {
        // write staged tile (registers -> LDS); safe: all Bb/SqC readers done
        *(uint4*)&Bb[ci * APAD + ch * 16] = pv0;
        *(uint4*)&Bb[ci * APAD + ch * 16 + 8] = pv1;
        if (tid < 64) SqC[tid] = psq;
        __syncthreads();   // barrier 1: Bb/SqC ready; prev selection done with Dt

        // MFMA phase: wave wv computes rows [wv*16, wv*16+16) x all 64 cands
#pragma unroll
        for (int ct = 0; ct < 4; ++ct) {
            const __bf16* bp = &Bb[(ct * 16 + n16) * APAD + quad * 8];
            bf16x8 bf0 = *(const bf16x8*)bp;
            bf16x8 bf1 = *(const bf16x8*)(bp + 32);
            f32x4 acc = {0.f, 0.f, 0.f, 0.f};
            acc = __builtin_amdgcn_mfma_f32_16x16x32_bf16(af0, bf0, acc, 0, 0, 0);
            acc = __builtin_amdgcn_mfma_f32_16x16x32_bf16(af1, bf1, acc, 0, 0, 0);
            const int ccol = ct * 16 + n16;
            const float sqc = SqC[ccol];
            const unsigned int m = (unsigned int)(t * 64 + ccol);
#pragma unroll
            for (int rr = 0; rr < 4; ++rr) {
                const int rrow = wv * 16 + quad * 4 + rr;
                Dt[rrow * DPAD + ccol] = packkey(fmaf(-2.0f, acc[rr], sqc), m);
            }
        }
        __syncthreads();   // barrier 2: Dt ready, Bb reads done

        // prefetch next tile into registers (latency hidden by selection)
        if (t < NN / 64 - 1) {
            const __bf16* src = fbf + (pbase + (long)(t + 1) * 64 + ci) * 64 + ch * 16;
            pv0 = *(const uint4*)src;
            pv1 = *(const uint4*)(src + 8);
            if (tid < 64) psq = sq[pbase + (t + 1) * 64 + tid];
        }

        // selection: thread (r, slot) sorts its 16 keys, merges into top-16
        {
            const uint4* kp = (const uint4*)&Dt[r * DPAD + slot * 16];
            unsigned int nk[16];
#pragma unroll
            for (int q = 0; q < 4; ++q) {
                uint4 kv = kp[q];
                nk[4 * q + 0] = kv.x; nk[4 * q + 1] = kv.y;
                nk[4 * q + 2] = kv.z; nk[4 * q + 3] = kv.w;
            }
            sort16(nk);
            merge16(keys, nk);
        }
    }

    // merge: reuse Dt as staging; 4 sorted lists -> 32-cand union superset
    __syncthreads();
    {
        uint4* kw = (uint4*)&Dt[r * DPAD + slot * 16];
#pragma unroll
        for (int q = 0; q < 4; ++q)
            kw[q] = make_uint4(keys[4 * q], keys[4 * q + 1], keys[4 * q + 2], keys[4 * q + 3]);
    }
    __syncthreads();
    if (slot < 2) {
        const unsigned int* k0 = &Dt[r * DPAD + slot * 32];
        const unsigned int* k1 = k0 + 16;
        unsigned short ms[16];
#pragma unroll
        for (int j = 0; j < 16; ++j) {
            unsigned int a = k0[j], bv = k1[15 - j];
            ms[j] = (unsigned short)((a < bv ? a : bv) & 0x7FFu);
        }
        uint4* op = (uint4*)(idx32 + ((pbase + row0 + r) * 32 + slot * 16));
        op[0] = ((const uint4*)ms)[0];
        op[1] = ((const uint4*)ms)[1];
    }
}

// ---------------------------------------------------------------------------
// Fused rescore + gather + edge-MLP, XCD-pinned batches. Block = 8 rows.
// D=64 gather uses a coalescing-optimal lane layout: 4 consecutive lanes read
// 4 consecutive 16B chunks of ONE candidate-row cache line.
// ---------------------------------------------------------------------------
template <int D>
__global__ __launch_bounds__(256) void rescore_gather_kernel(const float* __restrict__ feat,
                                                             const float* __restrict__ sq,
                                                             const unsigned short* __restrict__ idx32,
                                                             const float* __restrict__ P,
                                                             const float* __restrict__ Q,
                                                             const float* __restrict__ wo,
                                                             const float* __restrict__ bo,
                                                             float* __restrict__ outf) {
    __shared__ float rowf[8][D];
    __shared__ float Sc[8][32];
    __shared__ int Ji[8][32];
    __shared__ float Sq32[8][32];
    __shared__ int Li[8][KK];
    __shared__ float Rl[8][HH];
    const int tid = threadIdx.x;
    const int w = tid >> 6, ln = tid & 63;
    const int rw = ln >> 5, c = ln & 31;
    // batch->XCD pinning: each XCD's L2 sees only 4 batches' gather set
    const int xcd = blockIdx.x & 7;
    const int ii = blockIdx.x >> 3;            // 0..1023
    const int batch = xcd + 8 * (ii >> 8);     // 4 batches per XCD
    const int rb = ii & 255;
    const long pbase = (long)batch * NN;
    const long pblk = pbase + (long)rb * 8;
    const long p = pblk + w * 2 + rw;
    const int row_ = w * 2 + rw;

    for (int i = tid; i < 8 * D; i += 256) rowf[i / D][i % D] = feat[pblk * D + i];
    {
        const int j0 = (int)idx32[p * 32 + c];
        Ji[row_][c] = j0;
        Sq32[row_][c] = sq[pbase + j0];
    }
    __syncthreads();

    if constexpr (D == 64) {
        // gather + dot: lane = (cg, e); cg = cand-in-pass, e = 16B slot in line
        const int cg = ln >> 2, e = ln & 3;
#pragma unroll
        for (int rr = 0; rr < 2; ++rr) {
#pragma unroll
            for (int pp = 0; pp < 2; ++pp) {
                const int row = w * 2 + rr;
                const int cand = pp * 16 + cg;
                const int jj = Ji[row][cand];
                const float* cb = feat + (pbase + jj) * 64;
                float part = 0.f;
#pragma unroll
                for (int blk = 0; blk < 4; ++blk) {
                    float4 cv = *(const float4*)(cb + blk * 16 + e * 4);
                    float4 rv = *(const float4*)&rowf[row][blk * 16 + e * 4];
                    part = fmaf(rv.x, cv.x, part);
                    part = fmaf(rv.y, cv.y, part);
                    part = fmaf(rv.z, cv.z, part);
                    part = fmaf(rv.w, cv.w, part);
                }
                part += __shfl_xor(part, 1);
                part += __shfl_xor(part, 2);
                if (e == 0) Sc[row][cand] = fmaf(-2.0f, part, Sq32[row][cand]);
            }
        }
    } else {
        const int jj = Ji[row_][c];
        const float* cp = feat + (pbase + jj) * 3;
        float dot = fmaf(rowf[row_][0], cp[0],
                    fmaf(rowf[row_][1], cp[1], rowf[row_][2] * cp[2]));
        Sc[row_][c] = fmaf(-2.0f, dot, Sq32[row_][c]);
    }
    __syncthreads();

    // rank: exact lexicographic (score, j) over the 32 candidates (LDS broadcast)
    {
        const float score = Sc[row_][c];
        const int j = Ji[row_][c];
        int rank = 0;
#pragma unroll
        for (int m = 0; m < 32; ++m) {
            float dm = Sc[row_][m];
            int jm = Ji[row_][m];
            rank += (dm < score || (dm == score && jm < j)) ? 1 : 0;
        }
        if (rank < KK) Li[row_][rank] = j;
    }
    __syncthreads();

    // Phase 2: gather + MLP for the 8 rows
    const int h = tid & 63, pl = tid >> 6;
#pragma unroll
    for (int rr0 = 0; rr0 < 2; ++rr0) {
        const int rr = pl + rr0 * 4;
        const long pp = pblk + rr;
        const float Pv = P[pp * HH + h];
        float acc = 0.f;
#pragma unroll
        for (int k = 0; k < KK; ++k) {
            int j2 = Li[rr][k];
            acc += fmaxf(Pv + Q[(pbase + j2) * HH + h], 0.f);
        }
        Rl[rr][h] = acc * (1.f / KK);
    }
    __syncthreads();
#pragma unroll
    for (int rr0 = 0; rr0 < 2; ++rr0) {
        const int rr = pl + rr0 * 4;
        float o = bo[h];
#pragma unroll
        for (int l = 0; l < HH; ++l) o = fmaf(Rl[rr][l], wo[l * HH + h], o);
        outf[(pblk + rr) * HH + h] = o;
    }
}

// ---------------------------------------------------------------------------
// pool partial: block = (batch, chunk of 8); sums 256 rows -> pp[batch][ch][64]
// ---------------------------------------------------------------------------
__global__ __launch_bounds__(256) void pool_partial_kernel(const float* __restrict__ feat,
                                                           float* __restrict__ pp) {
    __shared__ float part[4][HH];
    const int batch = blockIdx.x >> 3;
    const int chk = blockIdx.x & 7;
    const int tid = threadIdx.x;
    const int h = tid & 63;
    const int sub = tid >> 6;
    float s = 0.f;
    const float* fp = feat + ((long)batch * NN + chk * 256 + sub * 64) * HH + h;
    for (int n = 0; n < 64; ++n) s += fp[(long)n * HH];
    part[sub][h] = s;
    __syncthreads();
    if (tid < HH)
        pp[(batch * 8 + chk) * HH + h] = part[0][h] + part[1][h] + part[2][h] + part[3][h];
}

// ---------------------------------------------------------------------------
// head: g[b] = mean; out[b] = relu(g@fw1+fb1)@fw2+fb2. Block = batch.
// ---------------------------------------------------------------------------
__global__ __launch_bounds__(256) void head_kernel(const float* __restrict__ pp,
                                                   const float* __restrict__ fw1,
                                                   const float* __restrict__ fb1,
                                                   const float* __restrict__ fw2,
                                                   const float* __restrict__ fb2,
                                                   float* __restrict__ out) {
    __shared__ float g[HH];
    __shared__ float tl[HH];
    const int b = blockIdx.x;
    const int tid = threadIdx.x;
    if (tid < HH) {
        float s = 0.f;
#pragma unroll
        for (int c = 0; c < 8; ++c) s += pp[(b * 8 + c) * HH + tid];
        g[tid] = s * (1.f / NN);
    }
    __syncthreads();
    if (tid < HH) {
        float a = fb1[tid];
#pragma unroll
        for (int l = 0; l < HH; ++l) a = fmaf(g[l], fw1[l * HH + tid], a);
        tl[tid] = fmaxf(a, 0.f);
    }
    __syncthreads();
    if (tid < OUTC) {
        float o = fb2[tid];
#pragma unroll
        for (int l = 0; l < HH; ++l) o = fmaf(tl[l], fw2[l * OUTC + tid], o);
        out[(long)b * OUTC + tid] = o;
    }
}

// ---------------------------------------------------------------------------
extern "C" void kernel_launch(void* const* d_in, const int* in_sizes, int n_in,
                              void* d_out, int out_size, void* d_ws, size_t ws_size,
                              hipStream_t stream) {
    const float* x    = (const float*)d_in[0];
    const float* w1_0 = (const float*)d_in[1];
    const float* b1_0 = (const float*)d_in[2];
    const float* wo_0 = (const float*)d_in[3];
    const float* bo_0 = (const float*)d_in[4];
    const float* w1_1 = (const float*)d_in[5];
    const float* b1_1 = (const float*)d_in[6];
    const float* wo_1 = (const float*)d_in[7];
    const float* bo_1 = (const float*)d_in[8];
    const float* w1_2 = (const float*)d_in[9];
    const float* b1_2 = (const float*)d_in[10];
    const float* wo_2 = (const float*)d_in[11];
    const float* bo_2 = (const float*)d_in[12];
    const float* fw1  = (const float*)d_in[13];
    const float* fb1  = (const float*)d_in[14];
    const float* fw2  = (const float*)d_in[15];
    const float* fb2  = (const float*)d_in[16];
    float* out = (float*)d_out;

    // workspace layout (floats)
    float* featA = (float*)d_ws;
    float* featB = featA + (long)BN * HH;
    float* Pb    = featB + (long)BN * HH;
    float* Qb    = Pb + (long)BN * HH;
    float* sqb   = Qb + (long)BN * HH;
    unsigned short* idx32 = (unsigned short*)(sqb + BN);     // BN x 32 u16
    float* ppb   = (float*)(idx32 + (long)BN * 32);          // 32 x 8 x 64

    // bf16 feature mirrors alias the OPPOSITE feature buffer (consumed by the
    // filter before rescore_gather rewrites that buffer)
    __bf16* fbf1 = (__bf16*)featB;   // layer 1 (featB rewritten after filter)
    __bf16* fbf2 = (__bf16*)featA;   // layer 2 (featA rewritten after filter)

    // ---- layer 0 (D=3, exact fp32 kNN) ----
    prep3_kernel<<<BN / 4, 256, 0, stream>>>(x, w1_0, b1_0, sqb, Pb, Qb);
    knn3_filter_kernel<<<BB * 32, 256, 0, stream>>>(x, sqb, idx32);
    rescore_gather_kernel<3><<<BN / 8, 256, 0, stream>>>(x, sqb, idx32, Pb, Qb, wo_0, bo_0, featA);

    // ---- layer 1 (D=64) ----
    prep64_kernel<<<BN / 64, 256, 0, stream>>>(featA, w1_1, b1_1, fbf1, sqb, Pb, Qb);
    knn_filter_kernel<<<BB * 32, 256, 0, stream>>>(fbf1, sqb, idx32);
    rescore_gather_kernel<64><<<BN / 8, 256, 0, stream>>>(featA, sqb, idx32, Pb, Qb, wo_1, bo_1, featB);

    // ---- layer 2 (D=64) ----
    prep64_kernel<<<BN / 64, 256, 0, stream>>>(featB, w1_2, b1_2, fbf2, sqb, Pb, Qb);
    knn_filter_kernel<<<BB * 32, 256, 0, stream>>>(fbf2, sqb, idx32);
    rescore_gather_kernel<64><<<BN / 8, 256, 0, stream>>>(featB, sqb, idx32, Pb, Qb, wo_2, bo_2, featA);

    // ---- pool + head ----
    pool_partial_kernel<<<BB * 8, 256, 0, stream>>>(featA, ppb);
    head_kernel<<<BB, 256, 0, stream>>>(ppb, fw1, fb1, fw2, fb2, out);
}